// Round 1
// baseline (831.984 us; speedup 1.0000x reference)
//
#include <hip/hip_runtime.h>

// Problem constants
#define BD      4
#define LSEQ    2048
#define DMODEL  1024
#define HHEADS  16
#define DKK     64
#define DFFN    4096
#define MROWS   (BD*LSEQ)   // 8192

typedef float  f32x4  __attribute__((ext_vector_type(4)));
typedef __bf16 bf16x8 __attribute__((ext_vector_type(8)));

__device__ inline unsigned short f2bf(float x) {
    union { float f; unsigned u; } c; c.f = x;
    unsigned r = c.u + 0x7FFFu + ((c.u >> 16) & 1u);
    return (unsigned short)(r >> 16);
}

// ---------------- f32 -> bf16 cast (grid-stride, float4 loads) ----------------
__global__ void cast_bf16_k(const float* __restrict__ in,
                            unsigned short* __restrict__ out, long n) {
    long i = ((long)blockIdx.x * blockDim.x + threadIdx.x) * 4;
    long stride = (long)gridDim.x * blockDim.x * 4;
    for (; i < n; i += stride) {
        float4 v = *(const float4*)(in + i);
        ushort4 o;
        o.x = f2bf(v.x); o.y = f2bf(v.y); o.z = f2bf(v.z); o.w = f2bf(v.w);
        *(ushort4*)(out + i) = o;
    }
}

// ---------------- async global->LDS 16B helper ----------------
__device__ inline void gload16(const void* g, void* l) {
    __builtin_amdgcn_global_load_lds(
        (const __attribute__((address_space(1))) void*)g,
        (__attribute__((address_space(3))) void*)l, 16, 0, 0);
}

// ---------------- NT GEMM: C[M,N] = A[M,K] * B[N,K]^T (+bias)(+resid)(relu) ----
// MODE 0: bf16 out ((acc+bias)*scale)
// MODE 1: bf16 out with ReLU
// MODE 2: f32 out + residual
template<int MODE>
__global__ __launch_bounds__(256) void gemm_nt(const unsigned short* __restrict__ A,
                                               const unsigned short* __restrict__ B,
                                               const float* __restrict__ bias,
                                               const float* __restrict__ resid,
                                               void* __restrict__ Cout,
                                               int M, int N, int K, float scale)
{
    __shared__ unsigned short As[128*32];
    __shared__ unsigned short Bs[128*32];
    const int t    = threadIdx.x;
    const int w    = t >> 6, lane = t & 63;
    const int r0   = lane & 15, g = lane >> 4;
    const int wm   = (w >> 1) * 64, wn = (w & 1) * 64;
    const int bm   = blockIdx.y * 128, bn = blockIdx.x * 128;
    const int srow = t >> 2, scol = (t & 3) * 8;

    const unsigned short* Ag = A + (size_t)(bm + srow) * K + scol;
    const unsigned short* Bg = B + (size_t)(bn + srow) * K + scol;
    unsigned short* AsW = As + w * 512;   // wave-uniform LDS base (byte w*1024)
    unsigned short* BsW = Bs + w * 512;

    f32x4 acc[4][4] = {};

    for (int kt = 0; kt < K; kt += 32) {
        gload16(Ag + kt,                   AsW);
        gload16(Ag + (size_t)64*K + kt,    AsW + 2048);
        gload16(Bg + kt,                   BsW);
        gload16(Bg + (size_t)64*K + kt,    BsW + 2048);
        __syncthreads();   // drains vmcnt -> LDS tiles ready
        bf16x8 af[4], bfr[4];
#pragma unroll
        for (int i = 0; i < 4; ++i)
            af[i] = *(const bf16x8*)(As + (wm + i*16 + r0)*32 + g*8);
#pragma unroll
        for (int j = 0; j < 4; ++j)
            bfr[j] = *(const bf16x8*)(Bs + (wn + j*16 + r0)*32 + g*8);
#pragma unroll
        for (int i = 0; i < 4; ++i)
#pragma unroll
            for (int j = 0; j < 4; ++j)
                acc[i][j] = __builtin_amdgcn_mfma_f32_16x16x32_bf16(af[i], bfr[j], acc[i][j], 0, 0, 0);
        __syncthreads();   // everyone done reading LDS before next stage
    }

#pragma unroll
    for (int i = 0; i < 4; ++i) {
        const int row0 = bm + wm + i*16 + g*4;
#pragma unroll
        for (int j = 0; j < 4; ++j) {
            const int col = bn + wn + j*16 + r0;
            const float bcol = bias[col];
#pragma unroll
            for (int rr = 0; rr < 4; ++rr) {
                const int row = row0 + rr;
                float c = (acc[i][j][rr] + bcol) * scale;
                if (MODE == 2) {
                    ((float*)Cout)[(size_t)row * N + col] = c + resid[(size_t)row * N + col];
                } else {
                    if (MODE == 1) c = fmaxf(c, 0.f);
                    ((unsigned short*)Cout)[(size_t)row * N + col] = f2bf(c);
                }
            }
        }
    }
}

// ---------------- fused flash attention ----------------
// 1 wave per 16 query rows of one (b,h). Q pre-scaled by 1/8.
// QK^T: S tile lane layout row=q_local=4g+r, col=key_local=r0 (per 16-key grp).
// Online softmax per q row (reduce across the 16 lanes of a g-group).
// P staged via LDS to A-fragment layout for the PV MFMA.
__global__ __launch_bounds__(64) void attn_k(
    const unsigned short* __restrict__ Q,
    const unsigned short* __restrict__ K,
    const unsigned short* __restrict__ V,
    const int* __restrict__ maskPAD,
    unsigned short* __restrict__ Z)
{
    const int lane = threadIdx.x;
    const int r0 = lane & 15, g = lane >> 4;
    const int qb = blockIdx.x;     // 0..127
    const int h  = blockIdx.y;     // 0..15
    const int b  = blockIdx.z;     // 0..3
    const int q0 = qb * 16;
    const size_t SR = DMODEL;      // row stride (H*DK)

    const unsigned short* Qb = Q + ((size_t)b * LSEQ + q0) * SR + h * DKK;
    bf16x8 aq[2];
#pragma unroll
    for (int ks = 0; ks < 2; ++ks)
        aq[ks] = *(const bf16x8*)(Qb + (size_t)r0 * SR + ks*32 + g*8);

    float m_r[4], l_r[4];
    f32x4 zacc[4];
#pragma unroll
    for (int r = 0; r < 4; ++r) { m_r[r] = -1e30f; l_r[r] = 0.f; }
#pragma unroll
    for (int d = 0; d < 4; ++d) zacc[d] = (f32x4){0.f, 0.f, 0.f, 0.f};

    __shared__ unsigned short Plds[16*32];
    const int* maskBase = maskPAD + ((size_t)b * LSEQ + q0) * LSEQ;

    for (int kt = 0; kt < LSEQ/32; ++kt) {
        const int k0 = kt * 32;
        const unsigned short* Kb = K + ((size_t)b * LSEQ + k0) * SR + h * DKK;
        f32x4 s[2];
#pragma unroll
        for (int grp = 0; grp < 2; ++grp) {
            bf16x8 bk0 = *(const bf16x8*)(Kb + (size_t)(grp*16 + r0) * SR + g*8);
            bf16x8 bk1 = *(const bf16x8*)(Kb + (size_t)(grp*16 + r0) * SR + 32 + g*8);
            f32x4 zz = {0.f, 0.f, 0.f, 0.f};
            zz = __builtin_amdgcn_mfma_f32_16x16x32_bf16(aq[0], bk0, zz, 0, 0, 0);
            zz = __builtin_amdgcn_mfma_f32_16x16x32_bf16(aq[1], bk1, zz, 0, 0, 0);
            s[grp] = zz;
        }
        // mask fill (finite -32767, matches reference semantics exactly)
#pragma unroll
        for (int grp = 0; grp < 2; ++grp)
#pragma unroll
            for (int r = 0; r < 4; ++r) {
                const int mq = 4*g + r;
                const int mk = k0 + grp*16 + r0;
                if (maskBase[(size_t)mq * LSEQ + mk] == 0) s[grp][r] = -32767.f;
            }
        // online softmax
        float p0[4], p1[4];
#pragma unroll
        for (int r = 0; r < 4; ++r) {
            float tm = fmaxf(s[0][r], s[1][r]);
            tm = fmaxf(tm, __shfl_xor(tm, 1));
            tm = fmaxf(tm, __shfl_xor(tm, 2));
            tm = fmaxf(tm, __shfl_xor(tm, 4));
            tm = fmaxf(tm, __shfl_xor(tm, 8));
            const float nm = fmaxf(m_r[r], tm);
            const float corr = __expf(m_r[r] - nm);
            const float e0 = __expf(s[0][r] - nm);
            const float e1 = __expf(s[1][r] - nm);
            float rs = e0 + e1;
            rs += __shfl_xor(rs, 1);
            rs += __shfl_xor(rs, 2);
            rs += __shfl_xor(rs, 4);
            rs += __shfl_xor(rs, 8);
            l_r[r] = l_r[r] * corr + rs;
            m_r[r] = nm;
            p0[r] = e0; p1[r] = e1;
#pragma unroll
            for (int d = 0; d < 4; ++d) zacc[d][r] *= corr;
        }
        // P -> LDS (bf16) in PV A-operand layout
#pragma unroll
        for (int r = 0; r < 4; ++r) {
            Plds[(4*g + r)*32 + r0]      = f2bf(p0[r]);
            Plds[(4*g + r)*32 + 16 + r0] = f2bf(p1[r]);
        }
        __syncthreads();
        bf16x8 ap = *(const bf16x8*)(Plds + r0*32 + g*8);
        const unsigned short* Vb = V + ((size_t)b * LSEQ + k0) * SR + h * DKK;
#pragma unroll
        for (int d = 0; d < 4; ++d) {
            union { bf16x8 v; unsigned short u[8]; } bv;
#pragma unroll
            for (int j = 0; j < 8; ++j)
                bv.u[j] = Vb[(size_t)(g*8 + j) * SR + d*16 + r0];
            zacc[d] = __builtin_amdgcn_mfma_f32_16x16x32_bf16(ap, bv.v, zacc[d], 0, 0, 0);
        }
        __syncthreads();
    }
    // epilogue: normalize and store bf16
    unsigned short* Zb = Z + ((size_t)b * LSEQ + q0) * SR + h * DKK;
#pragma unroll
    for (int d = 0; d < 4; ++d)
#pragma unroll
        for (int r = 0; r < 4; ++r) {
            const float val = zacc[d][r] / l_r[r];
            Zb[(size_t)(4*g + r) * SR + d*16 + r0] = f2bf(val);
        }
}

// ---------------- LayerNorm (f32 in -> bf16 out) ----------------
__global__ __launch_bounds__(256) void ln_k(const float* __restrict__ r,
                                            const float* __restrict__ gam,
                                            const float* __restrict__ bet,
                                            unsigned short* __restrict__ out)
{
    const int row = blockIdx.x;
    const int t = threadIdx.x;
    const float* rp = r + (size_t)row * DMODEL;
    float4 v = *(const float4*)(rp + t*4);
    float s  = v.x + v.y + v.z + v.w;
    float s2 = v.x*v.x + v.y*v.y + v.z*v.z + v.w*v.w;
#pragma unroll
    for (int off = 32; off >= 1; off >>= 1) {
        s  += __shfl_xor(s,  off);
        s2 += __shfl_xor(s2, off);
    }
    __shared__ float red[8];
    const int wv = t >> 6;
    if ((t & 63) == 0) { red[wv] = s; red[4 + wv] = s2; }
    __syncthreads();
    s  = red[0] + red[1] + red[2] + red[3];
    s2 = red[4] + red[5] + red[6] + red[7];
    const float mu   = s  * (1.f/DMODEL);
    const float var  = s2 * (1.f/DMODEL) - mu*mu;
    const float rstd = rsqrtf(var + 1e-5f);
    float4 gv = *(const float4*)(gam + t*4);
    float4 bv = *(const float4*)(bet + t*4);
    ushort4 o;
    o.x = f2bf((v.x - mu)*rstd*gv.x + bv.x);
    o.y = f2bf((v.y - mu)*rstd*gv.y + bv.y);
    o.z = f2bf((v.z - mu)*rstd*gv.z + bv.z);
    o.w = f2bf((v.w - mu)*rstd*gv.w + bv.w);
    *(ushort4*)(out + (size_t)row * DMODEL + t*4) = o;
}

extern "C" void kernel_launch(void* const* d_in, const int* in_sizes, int n_in,
                              void* d_out, int out_size, void* d_ws, size_t ws_size,
                              hipStream_t stream)
{
    const float* x    = (const float*)d_in[0];
    const int*   mask = (const int*)  d_in[1];
    const float* WQ_w = (const float*)d_in[2];
    const float* WQ_b = (const float*)d_in[3];
    const float* WK_w = (const float*)d_in[4];
    const float* WK_b = (const float*)d_in[5];
    const float* WV_w = (const float*)d_in[6];
    const float* WV_b = (const float*)d_in[7];
    const float* WO_w = (const float*)d_in[8];
    const float* WO_b = (const float*)d_in[9];
    const float* ln_g = (const float*)d_in[10];
    const float* ln_b = (const float*)d_in[11];
    const float* W1_w = (const float*)d_in[12];
    const float* W1_b = (const float*)d_in[13];
    const float* W2_w = (const float*)d_in[14];
    const float* W2_b = (const float*)d_in[15];
    float* out = (float*)d_out;

    char* w = (char*)d_ws;
    const size_t MB = 1024*1024;
    unsigned short* Qb  = (unsigned short*)(w + 0*MB);    // 16MB
    unsigned short* Kb  = (unsigned short*)(w + 16*MB);   // 16MB
    unsigned short* Vb  = (unsigned short*)(w + 32*MB);   // 16MB
    unsigned short* Zb  = (unsigned short*)(w + 48*MB);   // 16MB
    unsigned short* xb  = (unsigned short*)(w + 64*MB);   // 16MB
    float*          rb  = (float*)         (w + 80*MB);   // 32MB
    unsigned short* wqb = (unsigned short*)(w + 112*MB);  // 2MB
    unsigned short* wkb = (unsigned short*)(w + 114*MB);  // 2MB
    unsigned short* wvb = (unsigned short*)(w + 116*MB);  // 2MB
    unsigned short* wob = (unsigned short*)(w + 118*MB);  // 2MB
    unsigned short* w1b = (unsigned short*)(w + 120*MB);  // 8MB
    unsigned short* w2b = (unsigned short*)(w + 128*MB);  // 8MB -> top 136MB
    unsigned short* hln  = xb;                     // reuse (xb dead after QKV)
    unsigned short* hmid = (unsigned short*)(w + 0*MB);   // reuse Q..Z (64MB) after WO

    // casts
    cast_bf16_k<<<2048, 256, 0, stream>>>(x,    xb,  (long)MROWS*DMODEL);
    cast_bf16_k<<<512,  256, 0, stream>>>(WQ_w, wqb, (long)DMODEL*DMODEL);
    cast_bf16_k<<<512,  256, 0, stream>>>(WK_w, wkb, (long)DMODEL*DMODEL);
    cast_bf16_k<<<512,  256, 0, stream>>>(WV_w, wvb, (long)DMODEL*DMODEL);
    cast_bf16_k<<<512,  256, 0, stream>>>(WO_w, wob, (long)DMODEL*DMODEL);
    cast_bf16_k<<<2048, 256, 0, stream>>>(W1_w, w1b, (long)DFFN*DMODEL);
    cast_bf16_k<<<2048, 256, 0, stream>>>(W2_w, w2b, (long)DMODEL*DFFN);

    const dim3 blk(256);
    // Q/K/V projections (Q scaled by 1/8 — exact power-of-2 fold of 1/sqrt(DK))
    gemm_nt<0><<<dim3(8, 64), blk, 0, stream>>>(xb, wqb, WQ_b, nullptr, Qb, MROWS, DMODEL, DMODEL, 0.125f);
    gemm_nt<0><<<dim3(8, 64), blk, 0, stream>>>(xb, wkb, WK_b, nullptr, Kb, MROWS, DMODEL, DMODEL, 1.0f);
    gemm_nt<0><<<dim3(8, 64), blk, 0, stream>>>(xb, wvb, WV_b, nullptr, Vb, MROWS, DMODEL, DMODEL, 1.0f);
    // fused attention
    attn_k<<<dim3(LSEQ/16, HHEADS, BD), dim3(64), 0, stream>>>(Qb, Kb, Vb, mask, Zb);
    // WO projection + residual 1 -> r (f32)
    gemm_nt<2><<<dim3(8, 64), blk, 0, stream>>>(Zb, wob, WO_b, x, rb, MROWS, DMODEL, DMODEL, 1.0f);
    // pre-LN of FFN
    ln_k<<<MROWS, 256, 0, stream>>>(rb, ln_g, ln_b, hln);
    // FFN
    gemm_nt<1><<<dim3(32, 64), blk, 0, stream>>>(hln,  w1b, W1_b, nullptr, hmid, MROWS, DFFN,   DMODEL, 1.0f);
    gemm_nt<2><<<dim3(8, 64),  blk, 0, stream>>>(hmid, w2b, W2_b, rb,      out,  MROWS, DMODEL, DFFN,   1.0f);
}

// Round 2
// 643.566 us; speedup vs baseline: 1.2928x; 1.2928x over previous
//
#include <hip/hip_runtime.h>

// Problem constants
#define BD      4
#define LSEQ    2048
#define DMODEL  1024
#define HHEADS  16
#define DKK     64
#define DFFN    4096
#define MROWS   (BD*LSEQ)   // 8192

typedef float  f32x4  __attribute__((ext_vector_type(4)));
typedef __bf16 bf16x8 __attribute__((ext_vector_type(8)));
typedef unsigned short u16x8 __attribute__((ext_vector_type(8)));

__device__ inline unsigned short f2bf(float x) {
    union { float f; unsigned u; } c; c.f = x;
    unsigned r = c.u + 0x7FFFu + ((c.u >> 16) & 1u);
    return (unsigned short)(r >> 16);
}

// ---------------- f32 -> bf16 cast (grid-stride, float4 loads) ----------------
__global__ void cast_bf16_k(const float* __restrict__ in,
                            unsigned short* __restrict__ out, long n) {
    long i = ((long)blockIdx.x * blockDim.x + threadIdx.x) * 4;
    long stride = (long)gridDim.x * blockDim.x * 4;
    for (; i < n; i += stride) {
        float4 v = *(const float4*)(in + i);
        ushort4 o;
        o.x = f2bf(v.x); o.y = f2bf(v.y); o.z = f2bf(v.z); o.w = f2bf(v.w);
        *(ushort4*)(out + i) = o;
    }
}

// ---------------- async global->LDS 16B helper ----------------
__device__ inline void gload16(const void* g, void* l) {
    __builtin_amdgcn_global_load_lds(
        (const __attribute__((address_space(1))) void*)g,
        (__attribute__((address_space(3))) void*)l, 16, 0, 0);
}

// ---------------- NT GEMM: C[M,N] = A[M,K] * B[N,K]^T (+bias)(+resid)(relu) ----
// MODE 0: bf16 out ((acc+bias)*scale)
// MODE 1: bf16 out with ReLU
// MODE 2: f32 out + residual
template<int MODE>
__global__ __launch_bounds__(256) void gemm_nt(const unsigned short* __restrict__ A,
                                               const unsigned short* __restrict__ B,
                                               const float* __restrict__ bias,
                                               const float* __restrict__ resid,
                                               void* __restrict__ Cout,
                                               int M, int N, int K, float scale)
{
    __shared__ unsigned short As[128*32];
    __shared__ unsigned short Bs[128*32];
    const int t    = threadIdx.x;
    const int w    = t >> 6, lane = t & 63;
    const int r0   = lane & 15, g = lane >> 4;
    const int wm   = (w >> 1) * 64, wn = (w & 1) * 64;
    const int bm   = blockIdx.y * 128, bn = blockIdx.x * 128;
    const int srow = t >> 2, scol = (t & 3) * 8;

    const unsigned short* Ag = A + (size_t)(bm + srow) * K + scol;
    const unsigned short* Bg = B + (size_t)(bn + srow) * K + scol;
    unsigned short* AsW = As + w * 512;   // wave-uniform LDS base (byte w*1024)
    unsigned short* BsW = Bs + w * 512;

    f32x4 acc[4][4] = {};

    for (int kt = 0; kt < K; kt += 32) {
        gload16(Ag + kt,                   AsW);
        gload16(Ag + (size_t)64*K + kt,    AsW + 2048);
        gload16(Bg + kt,                   BsW);
        gload16(Bg + (size_t)64*K + kt,    BsW + 2048);
        __syncthreads();   // drains vmcnt -> LDS tiles ready
        bf16x8 af[4], bfr[4];
#pragma unroll
        for (int i = 0; i < 4; ++i)
            af[i] = *(const bf16x8*)(As + (wm + i*16 + r0)*32 + g*8);
#pragma unroll
        for (int j = 0; j < 4; ++j)
            bfr[j] = *(const bf16x8*)(Bs + (wn + j*16 + r0)*32 + g*8);
#pragma unroll
        for (int i = 0; i < 4; ++i)
#pragma unroll
            for (int j = 0; j < 4; ++j)
                acc[i][j] = __builtin_amdgcn_mfma_f32_16x16x32_bf16(af[i], bfr[j], acc[i][j], 0, 0, 0);
        __syncthreads();   // everyone done reading LDS before next stage
    }

#pragma unroll
    for (int i = 0; i < 4; ++i) {
        const int row0 = bm + wm + i*16 + g*4;
#pragma unroll
        for (int j = 0; j < 4; ++j) {
            const int col = bn + wn + j*16 + r0;
            const float bcol = bias[col];
#pragma unroll
            for (int rr = 0; rr < 4; ++rr) {
                const int row = row0 + rr;
                float c = (acc[i][j][rr] + bcol) * scale;
                if (MODE == 2) {
                    ((float*)Cout)[(size_t)row * N + col] = c + resid[(size_t)row * N + col];
                } else {
                    if (MODE == 1) c = fmaxf(c, 0.f);
                    ((unsigned short*)Cout)[(size_t)row * N + col] = f2bf(c);
                }
            }
        }
    }
}

// ---------------- fused flash attention (4 waves, 64 q-rows, 64-key tiles) ----
// Wave w owns q rows [q0+w*16, q0+w*16+16).
// K tile staged via global_load_lds with source-swizzled chunks:
//   LDS Ks[row][slot], data chunk c of row lives at slot = c ^ (row&7).
// V tile staged reg->LDS transposed: Vt[d][key'], key' = key ^ ((d&7)<<3).
// P per wave in swizzled LDS: Pl[w][q][k'], k' = k ^ ((q&7)<<3).
// S/C lane layout (m89): row(q) = 4g+rr, col = r0.
__global__ __launch_bounds__(256) void attn_k(
    const unsigned short* __restrict__ Q,
    const unsigned short* __restrict__ K,
    const unsigned short* __restrict__ V,
    const int* __restrict__ maskPAD,
    unsigned short* __restrict__ Z)
{
    __shared__ unsigned short Ks[64*64];     // 8 KB
    __shared__ unsigned short Vt[64*64];     // 8 KB (V transposed, swizzled)
    __shared__ unsigned short Pl[4][16*64];  // 8 KB (per-wave P)

    const int t    = threadIdx.x;
    const int w    = t >> 6, lane = t & 63;
    const int r0   = lane & 15, g = lane >> 4;
    const int q0   = blockIdx.x * 64;
    const int h    = blockIdx.y;
    const int b    = blockIdx.z;
    const int sw0  = (r0 & 7) << 3;          // read-side swizzle for Vt/P rows

    // Q fragments (Q pre-scaled by 1/8 in the projection GEMM)
    const unsigned short* Qg = Q + ((size_t)(b*LSEQ + q0 + w*16 + r0))*DMODEL + h*DKK;
    bf16x8 aq0 = *(const bf16x8*)(Qg + g*8);
    bf16x8 aq1 = *(const bf16x8*)(Qg + 32 + g*8);

    float m_r[4], l_r[4];
    f32x4 zacc[4];
#pragma unroll
    for (int rr = 0; rr < 4; ++rr) { m_r[rr] = -1e30f; l_r[rr] = 0.f; }
#pragma unroll
    for (int d0 = 0; d0 < 4; ++d0) zacc[d0] = (f32x4){0.f,0.f,0.f,0.f};

    const int* maskBase = maskPAD + ((size_t)(b*LSEQ) + q0 + w*16) * LSEQ;

    // staging thread mappings
    const int vkey   = t >> 2, vds = t & 3;         // V: key 0..63, d-seg 0..3
    const int krow_l = lane >> 3, kslot = lane & 7; // K: row-in-8, slot
    const int kchunk = kslot ^ (krow_l & 7);        // source chunk (swizzled)
    unsigned short* KsW = Ks + w*512;               // wave-uniform LDS base

    for (int kt = 0; kt < LSEQ/64; ++kt) {
        const int k0 = kt * 64;
        const unsigned short* KgB = K + ((size_t)(b*LSEQ + k0))*DMODEL + h*DKK;
        const unsigned short* VgB = V + ((size_t)(b*LSEQ + k0 + vkey))*DMODEL + h*DKK + vds*16;

        // V -> regs (coalesced: 4 threads cover 64B of one key row)
        u16x8 vv0 = *(const u16x8*)(VgB);
        u16x8 vv1 = *(const u16x8*)(VgB + 8);
        // K -> LDS direct (per-lane swizzled global source, linear LDS dest)
        gload16(KgB + (size_t)(w*8 + krow_l)*DMODEL + kchunk*8,      KsW);
        gload16(KgB + (size_t)(32 + w*8 + krow_l)*DMODEL + kchunk*8, KsW + 2048);
        // V^T scatter into swizzled LDS
#pragma unroll
        for (int i = 0; i < 8; ++i) {
            const int d = vds*16 + i;
            Vt[d*64 + (vkey ^ ((d&7)<<3))] = vv0[i];
        }
#pragma unroll
        for (int i = 0; i < 8; ++i) {
            const int d = vds*16 + 8 + i;
            Vt[d*64 + (vkey ^ ((d&7)<<3))] = vv1[i];
        }
        __syncthreads();   // drains gload_lds (vmcnt) + ds_writes (lgkm)

        // ---- QK^T: S[16q x 64k] per wave ----
        f32x4 s[4];
#pragma unroll
        for (int grp = 0; grp < 4; ++grp) {
            const int krow = grp*16 + r0;
            bf16x8 bk0 = *(const bf16x8*)(Ks + krow*64 + ((g     ^ (r0&7))<<3));
            bf16x8 bk1 = *(const bf16x8*)(Ks + krow*64 + (((4+g) ^ (r0&7))<<3));
            f32x4 zz = {0.f,0.f,0.f,0.f};
            zz = __builtin_amdgcn_mfma_f32_16x16x32_bf16(aq0, bk0, zz, 0, 0, 0);
            zz = __builtin_amdgcn_mfma_f32_16x16x32_bf16(aq1, bk1, zz, 0, 0, 0);
            s[grp] = zz;
        }

        // ---- mask fill ----
#pragma unroll
        for (int grp = 0; grp < 4; ++grp)
#pragma unroll
            for (int rr = 0; rr < 4; ++rr)
                if (maskBase[(size_t)(4*g+rr)*LSEQ + k0 + grp*16 + r0] == 0)
                    s[grp][rr] = -32767.f;

        // ---- online softmax (row reduce across 16 lanes of g-group) ----
#pragma unroll
        for (int rr = 0; rr < 4; ++rr) {
            float tm = fmaxf(fmaxf(s[0][rr], s[1][rr]), fmaxf(s[2][rr], s[3][rr]));
            tm = fmaxf(tm, __shfl_xor(tm, 1));
            tm = fmaxf(tm, __shfl_xor(tm, 2));
            tm = fmaxf(tm, __shfl_xor(tm, 4));
            tm = fmaxf(tm, __shfl_xor(tm, 8));
            const float nm   = fmaxf(m_r[rr], tm);
            const float corr = __expf(m_r[rr] - nm);
            const float e0 = __expf(s[0][rr] - nm);
            const float e1 = __expf(s[1][rr] - nm);
            const float e2 = __expf(s[2][rr] - nm);
            const float e3 = __expf(s[3][rr] - nm);
            float rs = (e0 + e1) + (e2 + e3);
            rs += __shfl_xor(rs, 1);
            rs += __shfl_xor(rs, 2);
            rs += __shfl_xor(rs, 4);
            rs += __shfl_xor(rs, 8);
            l_r[rr] = l_r[rr] * corr + rs;
            m_r[rr] = nm;
            // P writes (swizzled; per-wave buffer -> no barrier needed)
            const int q = 4*g + rr;
            unsigned short* Pq = Pl[w] + q*64;
            const int swq = (q & 7) << 3;
            Pq[(     r0) ^ swq] = f2bf(e0);
            Pq[(16 + r0) ^ swq] = f2bf(e1);
            Pq[(32 + r0) ^ swq] = f2bf(e2);
            Pq[(48 + r0) ^ swq] = f2bf(e3);
#pragma unroll
            for (int d0 = 0; d0 < 4; ++d0) zacc[d0][rr] *= corr;
        }

        // ---- PV: Z[16q x 64d] += P[16q x 64k] * V[64k x 64d] ----
        bf16x8 ap0 = *(const bf16x8*)(Pl[w] + r0*64 + ((g*8)      ^ sw0));
        bf16x8 ap1 = *(const bf16x8*)(Pl[w] + r0*64 + ((32 + g*8) ^ sw0));
#pragma unroll
        for (int d0 = 0; d0 < 4; ++d0) {
            const int drow = d0*16 + r0;
            bf16x8 bv0 = *(const bf16x8*)(Vt + drow*64 + ((g*8)      ^ sw0));
            bf16x8 bv1 = *(const bf16x8*)(Vt + drow*64 + ((32 + g*8) ^ sw0));
            zacc[d0] = __builtin_amdgcn_mfma_f32_16x16x32_bf16(ap0, bv0, zacc[d0], 0, 0, 0);
            zacc[d0] = __builtin_amdgcn_mfma_f32_16x16x32_bf16(ap1, bv1, zacc[d0], 0, 0, 0);
        }
        __syncthreads();   // all waves done reading Ks/Vt before next stage
    }

    // ---- epilogue: normalize, store bf16 ----
    unsigned short* Zb = Z + ((size_t)(b*LSEQ + q0 + w*16))*DMODEL + h*DKK;
#pragma unroll
    for (int d0 = 0; d0 < 4; ++d0)
#pragma unroll
        for (int rr = 0; rr < 4; ++rr)
            Zb[(size_t)(4*g+rr)*DMODEL + d0*16 + r0] = f2bf(zacc[d0][rr] / l_r[rr]);
}

// ---------------- LayerNorm (f32 in -> bf16 out) ----------------
__global__ __launch_bounds__(256) void ln_k(const float* __restrict__ r,
                                            const float* __restrict__ gam,
                                            const float* __restrict__ bet,
                                            unsigned short* __restrict__ out)
{
    const int row = blockIdx.x;
    const int t = threadIdx.x;
    const float* rp = r + (size_t)row * DMODEL;
    float4 v = *(const float4*)(rp + t*4);
    float s  = v.x + v.y + v.z + v.w;
    float s2 = v.x*v.x + v.y*v.y + v.z*v.z + v.w*v.w;
#pragma unroll
    for (int off = 32; off >= 1; off >>= 1) {
        s  += __shfl_xor(s,  off);
        s2 += __shfl_xor(s2, off);
    }
    __shared__ float red[8];
    const int wv = t >> 6;
    if ((t & 63) == 0) { red[wv] = s; red[4 + wv] = s2; }
    __syncthreads();
    s  = red[0] + red[1] + red[2] + red[3];
    s2 = red[4] + red[5] + red[6] + red[7];
    const float mu   = s  * (1.f/DMODEL);
    const float var  = s2 * (1.f/DMODEL) - mu*mu;
    const float rstd = rsqrtf(var + 1e-5f);
    float4 gv = *(const float4*)(gam + t*4);
    float4 bv = *(const float4*)(bet + t*4);
    ushort4 o;
    o.x = f2bf((v.x - mu)*rstd*gv.x + bv.x);
    o.y = f2bf((v.y - mu)*rstd*gv.y + bv.y);
    o.z = f2bf((v.z - mu)*rstd*gv.z + bv.z);
    o.w = f2bf((v.w - mu)*rstd*gv.w + bv.w);
    *(ushort4*)(out + (size_t)row * DMODEL + t*4) = o;
}

extern "C" void kernel_launch(void* const* d_in, const int* in_sizes, int n_in,
                              void* d_out, int out_size, void* d_ws, size_t ws_size,
                              hipStream_t stream)
{
    const float* x    = (const float*)d_in[0];
    const int*   mask = (const int*)  d_in[1];
    const float* WQ_w = (const float*)d_in[2];
    const float* WQ_b = (const float*)d_in[3];
    const float* WK_w = (const float*)d_in[4];
    const float* WK_b = (const float*)d_in[5];
    const float* WV_w = (const float*)d_in[6];
    const float* WV_b = (const float*)d_in[7];
    const float* WO_w = (const float*)d_in[8];
    const float* WO_b = (const float*)d_in[9];
    const float* ln_g = (const float*)d_in[10];
    const float* ln_b = (const float*)d_in[11];
    const float* W1_w = (const float*)d_in[12];
    const float* W1_b = (const float*)d_in[13];
    const float* W2_w = (const float*)d_in[14];
    const float* W2_b = (const float*)d_in[15];
    float* out = (float*)d_out;

    char* w = (char*)d_ws;
    const size_t MB = 1024*1024;
    unsigned short* Qb  = (unsigned short*)(w + 0*MB);    // 16MB
    unsigned short* Kb  = (unsigned short*)(w + 16*MB);   // 16MB
    unsigned short* Vb  = (unsigned short*)(w + 32*MB);   // 16MB
    unsigned short* Zb  = (unsigned short*)(w + 48*MB);   // 16MB
    unsigned short* xb  = (unsigned short*)(w + 64*MB);   // 16MB
    float*          rb  = (float*)         (w + 80*MB);   // 32MB
    unsigned short* wqb = (unsigned short*)(w + 112*MB);  // 2MB
    unsigned short* wkb = (unsigned short*)(w + 114*MB);  // 2MB
    unsigned short* wvb = (unsigned short*)(w + 116*MB);  // 2MB
    unsigned short* wob = (unsigned short*)(w + 118*MB);  // 2MB
    unsigned short* w1b = (unsigned short*)(w + 120*MB);  // 8MB
    unsigned short* w2b = (unsigned short*)(w + 128*MB);  // 8MB -> top 136MB
    unsigned short* hln  = xb;                     // reuse (xb dead after QKV)
    unsigned short* hmid = (unsigned short*)(w + 0*MB);   // reuse Q..Z (64MB) after WO

    // casts
    cast_bf16_k<<<2048, 256, 0, stream>>>(x,    xb,  (long)MROWS*DMODEL);
    cast_bf16_k<<<512,  256, 0, stream>>>(WQ_w, wqb, (long)DMODEL*DMODEL);
    cast_bf16_k<<<512,  256, 0, stream>>>(WK_w, wkb, (long)DMODEL*DMODEL);
    cast_bf16_k<<<512,  256, 0, stream>>>(WV_w, wvb, (long)DMODEL*DMODEL);
    cast_bf16_k<<<512,  256, 0, stream>>>(WO_w, wob, (long)DMODEL*DMODEL);
    cast_bf16_k<<<2048, 256, 0, stream>>>(W1_w, w1b, (long)DFFN*DMODEL);
    cast_bf16_k<<<2048, 256, 0, stream>>>(W2_w, w2b, (long)DMODEL*DFFN);

    const dim3 blk(256);
    // Q/K/V projections (Q scaled by 1/8 — exact power-of-2 fold of 1/sqrt(DK))
    gemm_nt<0><<<dim3(8, 64), blk, 0, stream>>>(xb, wqb, WQ_b, nullptr, Qb, MROWS, DMODEL, DMODEL, 0.125f);
    gemm_nt<0><<<dim3(8, 64), blk, 0, stream>>>(xb, wkb, WK_b, nullptr, Kb, MROWS, DMODEL, DMODEL, 1.0f);
    gemm_nt<0><<<dim3(8, 64), blk, 0, stream>>>(xb, wvb, WV_b, nullptr, Vb, MROWS, DMODEL, DMODEL, 1.0f);
    // fused attention: 64 q-rows per block, 4 waves
    attn_k<<<dim3(LSEQ/64, HHEADS, BD), dim3(256), 0, stream>>>(Qb, Kb, Vb, mask, Zb);
    // WO projection + residual 1 -> r (f32)
    gemm_nt<2><<<dim3(8, 64), blk, 0, stream>>>(Zb, wob, WO_b, x, rb, MROWS, DMODEL, DMODEL, 1.0f);
    // pre-LN of FFN
    ln_k<<<MROWS, 256, 0, stream>>>(rb, ln_g, ln_b, hln);
    // FFN
    gemm_nt<1><<<dim3(32, 64), blk, 0, stream>>>(hln,  w1b, W1_b, nullptr, hmid, MROWS, DFFN,   DMODEL, 1.0f);
    gemm_nt<2><<<dim3(8, 64),  blk, 0, stream>>>(hmid, w2b, W2_b, rb,      out,  MROWS, DMODEL, DFFN,   1.0f);
}

// Round 3
// 569.769 us; speedup vs baseline: 1.4602x; 1.1295x over previous
//
#include <hip/hip_runtime.h>

// Problem constants
#define BD      4
#define LSEQ    2048
#define DMODEL  1024
#define HHEADS  16
#define DKK     64
#define DFFN    4096
#define MROWS   (BD*LSEQ)   // 8192

typedef float  f32x4  __attribute__((ext_vector_type(4)));
typedef float  f32x16 __attribute__((ext_vector_type(16)));
typedef __bf16 bf16x8 __attribute__((ext_vector_type(8)));
typedef unsigned short u16x8 __attribute__((ext_vector_type(8)));
typedef unsigned int   u32x4 __attribute__((ext_vector_type(4)));

__device__ inline unsigned short f2bf(float x) {
    union { float f; unsigned u; } c; c.f = x;
    unsigned r = c.u + 0x7FFFu + ((c.u >> 16) & 1u);
    return (unsigned short)(r >> 16);
}

// ---------------- f32 -> bf16 cast (grid-stride, float4 loads) ----------------
__global__ void cast_bf16_k(const float* __restrict__ in,
                            unsigned short* __restrict__ out, long n) {
    long i = ((long)blockIdx.x * blockDim.x + threadIdx.x) * 4;
    long stride = (long)gridDim.x * blockDim.x * 4;
    for (; i < n; i += stride) {
        float4 v = *(const float4*)(in + i);
        ushort4 o;
        o.x = f2bf(v.x); o.y = f2bf(v.y); o.z = f2bf(v.z); o.w = f2bf(v.w);
        *(ushort4*)(out + i) = o;
    }
}

// ---------------- mask -> bitmask (one u64 word per wave via ballot) ----------
// layout: bits[(b*32 + kt)*LSEQ + q]  (kt = 64-key tile index)
__global__ __launch_bounds__(256) void maskbits_k(const int* __restrict__ m,
                                                  unsigned long long* __restrict__ bits) {
    const long gw = ((long)blockIdx.x * blockDim.x + threadIdx.x) >> 6;
    const int lane = threadIdx.x & 63;
    const int b   = (int)(gw >> 16);          // 2048*32 words per batch
    const int rem = (int)gw & 65535;
    const int q = rem >> 5, kt = rem & 31;
    const int v = m[((size_t)(b*LSEQ + q))*LSEQ + kt*64 + lane];
    const unsigned long long bal = __ballot(v != 0);
    if (lane == 0) bits[((size_t)(b*32 + kt))*LSEQ + q] = bal;
}

// ---------------- async global->LDS 16B helper ----------------
__device__ inline void gload16(const void* g, void* l) {
    __builtin_amdgcn_global_load_lds(
        (const __attribute__((address_space(1))) void*)g,
        (__attribute__((address_space(3))) void*)l, 16, 0, 0);
}

// ---------------- NT GEMM: C[M,N] = A[M,K] * B[N,K]^T (+bias)(+resid)(relu) ----
template<int MODE>
__global__ __launch_bounds__(256) void gemm_nt(const unsigned short* __restrict__ A,
                                               const unsigned short* __restrict__ B,
                                               const float* __restrict__ bias,
                                               const float* __restrict__ resid,
                                               void* __restrict__ Cout,
                                               int M, int N, int K, float scale)
{
    __shared__ unsigned short As[128*32];
    __shared__ unsigned short Bs[128*32];
    const int t    = threadIdx.x;
    const int w    = t >> 6, lane = t & 63;
    const int r0   = lane & 15, g = lane >> 4;
    const int wm   = (w >> 1) * 64, wn = (w & 1) * 64;
    const int bm   = blockIdx.y * 128, bn = blockIdx.x * 128;
    const int srow = t >> 2, scol = (t & 3) * 8;

    const unsigned short* Ag = A + (size_t)(bm + srow) * K + scol;
    const unsigned short* Bg = B + (size_t)(bn + srow) * K + scol;
    unsigned short* AsW = As + w * 512;
    unsigned short* BsW = Bs + w * 512;

    f32x4 acc[4][4] = {};

    for (int kt = 0; kt < K; kt += 32) {
        gload16(Ag + kt,                   AsW);
        gload16(Ag + (size_t)64*K + kt,    AsW + 2048);
        gload16(Bg + kt,                   BsW);
        gload16(Bg + (size_t)64*K + kt,    BsW + 2048);
        __syncthreads();
        bf16x8 af[4], bfr[4];
#pragma unroll
        for (int i = 0; i < 4; ++i)
            af[i] = *(const bf16x8*)(As + (wm + i*16 + r0)*32 + g*8);
#pragma unroll
        for (int j = 0; j < 4; ++j)
            bfr[j] = *(const bf16x8*)(Bs + (wn + j*16 + r0)*32 + g*8);
#pragma unroll
        for (int i = 0; i < 4; ++i)
#pragma unroll
            for (int j = 0; j < 4; ++j)
                acc[i][j] = __builtin_amdgcn_mfma_f32_16x16x32_bf16(af[i], bfr[j], acc[i][j], 0, 0, 0);
        __syncthreads();
    }

#pragma unroll
    for (int i = 0; i < 4; ++i) {
        const int row0 = bm + wm + i*16 + g*4;
#pragma unroll
        for (int j = 0; j < 4; ++j) {
            const int col = bn + wn + j*16 + r0;
            const float bcol = bias[col];
#pragma unroll
            for (int rr = 0; rr < 4; ++rr) {
                const int row = row0 + rr;
                float c = (acc[i][j][rr] + bcol) * scale;
                if (MODE == 2) {
                    ((float*)Cout)[(size_t)row * N + col] = c + resid[(size_t)row * N + col];
                } else {
                    if (MODE == 1) c = fmaxf(c, 0.f);
                    ((unsigned short*)Cout)[(size_t)row * N + col] = f2bf(c);
                }
            }
        }
    }
}

// ---------------- fused flash attention (swapped QK^T, 32x32x16 MFMA) --------
// Block: 4 waves x 32 q-rows = 128 q. Wave computes S^T = K*Q^T so each lane
// owns one q-row (q = lane&31); P stays in registers (cvt_pk + permlane32_swap
// build the PV A-fragments). Mask from bitmask words. K double-buffered via
// source-swizzled global_load_lds; V^T reg-staged with XOR swizzle.
__global__ __launch_bounds__(256) void attn_k(
    const unsigned short* __restrict__ Q,
    const unsigned short* __restrict__ K,
    const unsigned short* __restrict__ V,
    const unsigned long long* __restrict__ MBits,
    unsigned short* __restrict__ Z)
{
    __shared__ unsigned short Ks[2][64*64];   // 16 KB (double buffer)
    __shared__ unsigned short Vt[64*64];      // 8 KB  (V transposed, swizzled)
    __shared__ float Sc[4*32];                // per-wave broadcast scratch

    const int t    = threadIdx.x;
    const int w    = t >> 6, lane = t & 63;
    const int q31  = lane & 31, hi = lane >> 5;

    // XCD-friendly block swizzle: keep the 16 blocks sharing (h,b) on one XCD
    const int bid = blockIdx.x;
    const int sw  = (bid & 7) * 128 + (bid >> 3);
    const int qt  = sw & 15, h = (sw >> 4) & 15, b = sw >> 8;
    const int qw  = qt * 128 + w * 32;        // wave q base

    // ---- Q fragments (pre-scaled by 1/8 in projection) ----
    const unsigned short* Qg = Q + ((size_t)(b*LSEQ + qw + q31))*DMODEL + h*DKK + hi*8;
    bf16x8 qf[4];
#pragma unroll
    for (int ds = 0; ds < 4; ++ds)
        qf[ds] = *(const bf16x8*)(Qg + ds*16);

    // staging mappings
    const int krow  = w*8 + (lane>>3);            // K row (and +32)
    const int kchk  = (lane & 7) ^ (krow & 7);    // swizzled source chunk
    const unsigned short* Kg = K + ((size_t)(b*LSEQ))*DMODEL + h*DKK;
    const int kp   = w*8 + (lane>>3);             // V key-pair index
    const int vd0  = (lane & 7) * 8;              // V d-slice base
    const unsigned short* Vg = V + ((size_t)(b*LSEQ))*DMODEL + h*DKK + vd0;

    float m_r = -32767.f, l_r = 0.f;
    f32x16 z0, z1;
#pragma unroll
    for (int r = 0; r < 16; ++r) { z0[r] = 0.f; z1[r] = 0.f; }

    const float L2E = 1.44269504f;

    // ---- prologue: stage tile 0 ----
    u16x8 vA = *(const u16x8*)(Vg + (size_t)(kp*2)*DMODEL);
    u16x8 vB = *(const u16x8*)(Vg + (size_t)(kp*2+1)*DMODEL);
#pragma unroll
    for (int i = 0; i < 8; ++i) {
        const int d = vd0 + i;
        const int c = (kp>>2) ^ (d&7) ^ (d>>3);
        *(unsigned*)&Vt[d*64 + c*8 + 2*(kp&3)] = (unsigned)vA[i] | ((unsigned)vB[i] << 16);
    }
    gload16(Kg + (size_t)krow*DMODEL      + kchk*8, &Ks[0][w*512]);
    gload16(Kg + (size_t)(32+krow)*DMODEL + kchk*8, &Ks[0][w*512] + 2048);

    for (int kt = 0; kt < LSEQ/64; ++kt) {
        const int cur = kt & 1;
        __syncthreads();   // A: Ks[cur] + Vt for this tile ready

        // early-issue next tile's loads (latency hides under compute)
        if (kt < LSEQ/64 - 1) {
            const int k0n = (kt+1)*64;
            gload16(Kg + (size_t)(k0n + krow)*DMODEL      + kchk*8, &Ks[cur^1][w*512]);
            gload16(Kg + (size_t)(k0n + 32 + krow)*DMODEL + kchk*8, &Ks[cur^1][w*512] + 2048);
            vA = *(const u16x8*)(Vg + (size_t)(k0n + kp*2)*DMODEL);
            vB = *(const u16x8*)(Vg + (size_t)(k0n + kp*2+1)*DMODEL);
        }
        // mask word for this q-row / key-tile
        const unsigned long long mw = MBits[((size_t)(b*32 + kt))*LSEQ + (qw + q31)];
        const unsigned long long sh = mw >> (hi*4);
        const unsigned md0 = (unsigned)sh, md1 = (unsigned)(sh >> 32);

        // ---- QK^T (swapped): s = K_tile * Q^T ----
        f32x16 s0, s1;
#pragma unroll
        for (int r = 0; r < 16; ++r) { s0[r] = 0.f; s1[r] = 0.f; }
        __builtin_amdgcn_s_setprio(1);
#pragma unroll
        for (int ds = 0; ds < 4; ++ds) {
            const int slot = ((ds*2 + hi) ^ (q31 & 7)) << 3;
            bf16x8 kf0 = *(const bf16x8*)(&Ks[cur][ q31     *64 + slot]);
            bf16x8 kf1 = *(const bf16x8*)(&Ks[cur][(32+q31)*64 + slot]);
            s0 = __builtin_amdgcn_mfma_f32_32x32x16_bf16(kf0, qf[ds], s0, 0, 0, 0);
            s1 = __builtin_amdgcn_mfma_f32_32x32x16_bf16(kf1, qf[ds], s1, 0, 0, 0);
        }
        __builtin_amdgcn_s_setprio(0);

        // ---- mask fill ----
#pragma unroll
        for (int r = 0; r < 16; ++r) {
            const int kb = (r & 3) + 8*(r >> 2);
            if (!((md0 >> kb) & 1)) s0[r] = -32767.f;
            if (!((md1 >> kb) & 1)) s1[r] = -32767.f;
        }

        // ---- row max (local chain + one cross-half swap) ----
        float tm = fmaxf(s0[0], s1[0]);
#pragma unroll
        for (int r = 1; r < 16; ++r) tm = fmaxf(tm, fmaxf(s0[r], s1[r]));
        {
            float ta = tm, tb = tm;
            asm volatile("v_permlane32_swap_b32 %0, %1" : "+v"(ta), "+v"(tb));
            tm = fmaxf(tm, hi ? ta : tb);
        }

        // ---- defer-max rescale (rare) ----
        if (__any(tm > m_r + 8.f)) {
            const float nm   = fmaxf(m_r, tm);
            const float corr = exp2f((m_r - nm) * L2E);
            Sc[w*32 + q31] = corr;
            l_r *= corr;
            m_r  = nm;
#pragma unroll
            for (int r = 0; r < 16; ++r) {
                const int row = (r & 3) + 8*(r >> 2) + 4*hi;
                const float cr = Sc[w*32 + row];
                z0[r] *= cr; z1[r] *= cr;
            }
        }

        // ---- exp ----
        const float mL = m_r * L2E;
#pragma unroll
        for (int r = 0; r < 16; ++r) {
            s0[r] = exp2f(s0[r]*L2E - mL);
            s1[r] = exp2f(s1[r]*L2E - mL);
        }
        // ---- row sum (tree + cross-half swap) ----
        float r4[8];
#pragma unroll
        for (int r = 0; r < 8; ++r)
            r4[r] = (s0[2*r] + s0[2*r+1]) + (s1[2*r] + s1[2*r+1]);
        float rs = ((r4[0]+r4[1]) + (r4[2]+r4[3])) + ((r4[4]+r4[5]) + (r4[6]+r4[7]));
        {
            float ra = rs, rb = rs;
            asm volatile("v_permlane32_swap_b32 %0, %1" : "+v"(ra), "+v"(rb));
            rs += hi ? ra : rb;
        }
        l_r += rs;

        // ---- P -> bf16 A-frags in-register (cvt_pk + permlane32_swap) ----
        bf16x8 pa[4];
#pragma unroll
        for (int half = 0; half < 2; ++half) {
#pragma unroll
            for (int sub = 0; sub < 2; ++sub) {
                const int base = sub*8;
                unsigned wa, wb, wc, wd;
                float p0 = half ? s1[base+0] : s0[base+0];
                float p1 = half ? s1[base+1] : s0[base+1];
                float p2 = half ? s1[base+2] : s0[base+2];
                float p3 = half ? s1[base+3] : s0[base+3];
                float p4 = half ? s1[base+4] : s0[base+4];
                float p5 = half ? s1[base+5] : s0[base+5];
                float p6 = half ? s1[base+6] : s0[base+6];
                float p7 = half ? s1[base+7] : s0[base+7];
                asm("v_cvt_pk_bf16_f32 %0, %1, %2" : "=v"(wa) : "v"(p0), "v"(p1));
                asm("v_cvt_pk_bf16_f32 %0, %1, %2" : "=v"(wb) : "v"(p4), "v"(p5));
                asm("v_cvt_pk_bf16_f32 %0, %1, %2" : "=v"(wc) : "v"(p2), "v"(p3));
                asm("v_cvt_pk_bf16_f32 %0, %1, %2" : "=v"(wd) : "v"(p6), "v"(p7));
                asm volatile("v_permlane32_swap_b32 %0, %1" : "+v"(wa), "+v"(wb));
                asm volatile("v_permlane32_swap_b32 %0, %1" : "+v"(wc), "+v"(wd));
                u32x4 pu; pu[0] = wa; pu[1] = wc; pu[2] = wb; pu[3] = wd;
                pa[half*2 + sub] = __builtin_bit_cast(bf16x8, pu);
            }
        }

        // ---- PV: Z^T[q][d] += P*V ----
        __builtin_amdgcn_s_setprio(1);
#pragma unroll
        for (int ks = 0; ks < 4; ++ks) {
            const int ch = ks*2 + hi;
            bf16x8 vf0 = *(const bf16x8*)(&Vt[ q31     *64 + ((ch ^ (q31&7) ^ ( q31>>3)     ) << 3)]);
            bf16x8 vf1 = *(const bf16x8*)(&Vt[(32+q31)*64 + ((ch ^ (q31&7) ^ ((32+q31)>>3)) << 3)]);
            z0 = __builtin_amdgcn_mfma_f32_32x32x16_bf16(pa[ks], vf0, z0, 0, 0, 0);
            z1 = __builtin_amdgcn_mfma_f32_32x32x16_bf16(pa[ks], vf1, z1, 0, 0, 0);
        }
        __builtin_amdgcn_s_setprio(0);

        __syncthreads();   // B: everyone done reading Ks[cur] + Vt

        // write next tile's V^T (regs loaded early this iteration)
        if (kt < LSEQ/64 - 1) {
#pragma unroll
            for (int i = 0; i < 8; ++i) {
                const int d = vd0 + i;
                const int c = (kp>>2) ^ (d&7) ^ (d>>3);
                *(unsigned*)&Vt[d*64 + c*8 + 2*(kp&3)] = (unsigned)vA[i] | ((unsigned)vB[i] << 16);
            }
        }
    }

    // ---- epilogue: broadcast l per row, normalize, store ----
    Sc[w*32 + q31] = l_r;
    unsigned short* Zb = Z + ((size_t)(b*LSEQ + qw))*DMODEL + h*DKK + q31;
#pragma unroll
    for (int r = 0; r < 16; ++r) {
        const int row = (r & 3) + 8*(r >> 2) + 4*hi;
        const float rl = 1.0f / Sc[w*32 + row];
        Zb[(size_t)row*DMODEL]      = f2bf(z0[r] * rl);
        Zb[(size_t)row*DMODEL + 32] = f2bf(z1[r] * rl);
    }
}

// ---------------- LayerNorm (f32 in -> bf16 out) ----------------
__global__ __launch_bounds__(256) void ln_k(const float* __restrict__ r,
                                            const float* __restrict__ gam,
                                            const float* __restrict__ bet,
                                            unsigned short* __restrict__ out)
{
    const int row = blockIdx.x;
    const int t = threadIdx.x;
    const float* rp = r + (size_t)row * DMODEL;
    float4 v = *(const float4*)(rp + t*4);
    float s  = v.x + v.y + v.z + v.w;
    float s2 = v.x*v.x + v.y*v.y + v.z*v.z + v.w*v.w;
#pragma unroll
    for (int off = 32; off >= 1; off >>= 1) {
        s  += __shfl_xor(s,  off);
        s2 += __shfl_xor(s2, off);
    }
    __shared__ float red[8];
    const int wv = t >> 6;
    if ((t & 63) == 0) { red[wv] = s; red[4 + wv] = s2; }
    __syncthreads();
    s  = red[0] + red[1] + red[2] + red[3];
    s2 = red[4] + red[5] + red[6] + red[7];
    const float mu   = s  * (1.f/DMODEL);
    const float var  = s2 * (1.f/DMODEL) - mu*mu;
    const float rstd = rsqrtf(var + 1e-5f);
    float4 gv = *(const float4*)(gam + t*4);
    float4 bv = *(const float4*)(bet + t*4);
    ushort4 o;
    o.x = f2bf((v.x - mu)*rstd*gv.x + bv.x);
    o.y = f2bf((v.y - mu)*rstd*gv.y + bv.y);
    o.z = f2bf((v.z - mu)*rstd*gv.z + bv.z);
    o.w = f2bf((v.w - mu)*rstd*gv.w + bv.w);
    *(ushort4*)(out + (size_t)row * DMODEL + t*4) = o;
}

extern "C" void kernel_launch(void* const* d_in, const int* in_sizes, int n_in,
                              void* d_out, int out_size, void* d_ws, size_t ws_size,
                              hipStream_t stream)
{
    const float* x    = (const float*)d_in[0];
    const int*   mask = (const int*)  d_in[1];
    const float* WQ_w = (const float*)d_in[2];
    const float* WQ_b = (const float*)d_in[3];
    const float* WK_w = (const float*)d_in[4];
    const float* WK_b = (const float*)d_in[5];
    const float* WV_w = (const float*)d_in[6];
    const float* WV_b = (const float*)d_in[7];
    const float* WO_w = (const float*)d_in[8];
    const float* WO_b = (const float*)d_in[9];
    const float* ln_g = (const float*)d_in[10];
    const float* ln_b = (const float*)d_in[11];
    const float* W1_w = (const float*)d_in[12];
    const float* W1_b = (const float*)d_in[13];
    const float* W2_w = (const float*)d_in[14];
    const float* W2_b = (const float*)d_in[15];
    float* out = (float*)d_out;

    char* w = (char*)d_ws;
    const size_t MB = 1024*1024;
    unsigned short* Qb  = (unsigned short*)(w + 0*MB);    // 16MB
    unsigned short* Kb  = (unsigned short*)(w + 16*MB);   // 16MB
    unsigned short* Vb  = (unsigned short*)(w + 32*MB);   // 16MB
    unsigned short* Zb  = (unsigned short*)(w + 48*MB);   // 16MB
    unsigned short* xb  = (unsigned short*)(w + 64*MB);   // 16MB
    float*          rb  = (float*)         (w + 80*MB);   // 32MB
    unsigned short* wqb = (unsigned short*)(w + 112*MB);  // 2MB
    unsigned short* wkb = (unsigned short*)(w + 114*MB);  // 2MB
    unsigned short* wvb = (unsigned short*)(w + 116*MB);  // 2MB
    unsigned short* wob = (unsigned short*)(w + 118*MB);  // 2MB
    unsigned short* w1b = (unsigned short*)(w + 120*MB);  // 8MB
    unsigned short* w2b = (unsigned short*)(w + 128*MB);  // 8MB
    unsigned long long* mbits = (unsigned long long*)(w + 136*MB); // 2MB -> 138MB
    unsigned short* hln  = xb;                     // reuse (xb dead after QKV)
    unsigned short* hmid = (unsigned short*)(w + 0*MB);   // reuse Q..Z after WO

    // casts + mask bitmask
    cast_bf16_k<<<2048, 256, 0, stream>>>(x,    xb,  (long)MROWS*DMODEL);
    cast_bf16_k<<<512,  256, 0, stream>>>(WQ_w, wqb, (long)DMODEL*DMODEL);
    cast_bf16_k<<<512,  256, 0, stream>>>(WK_w, wkb, (long)DMODEL*DMODEL);
    cast_bf16_k<<<512,  256, 0, stream>>>(WV_w, wvb, (long)DMODEL*DMODEL);
    cast_bf16_k<<<512,  256, 0, stream>>>(WO_w, wob, (long)DMODEL*DMODEL);
    cast_bf16_k<<<2048, 256, 0, stream>>>(W1_w, w1b, (long)DFFN*DMODEL);
    cast_bf16_k<<<2048, 256, 0, stream>>>(W2_w, w2b, (long)DMODEL*DFFN);
    maskbits_k<<<65536, 256, 0, stream>>>(mask, mbits);

    const dim3 blk(256);
    // Q/K/V projections (Q scaled by 1/8 — exact power-of-2 fold of 1/sqrt(DK))
    gemm_nt<0><<<dim3(8, 64), blk, 0, stream>>>(xb, wqb, WQ_b, nullptr, Qb, MROWS, DMODEL, DMODEL, 0.125f);
    gemm_nt<0><<<dim3(8, 64), blk, 0, stream>>>(xb, wkb, WK_b, nullptr, Kb, MROWS, DMODEL, DMODEL, 1.0f);
    gemm_nt<0><<<dim3(8, 64), blk, 0, stream>>>(xb, wvb, WV_b, nullptr, Vb, MROWS, DMODEL, DMODEL, 1.0f);
    // fused attention: 128 q-rows per block (4 waves x 32q), 1D swizzled grid
    attn_k<<<dim3(1024), dim3(256), 0, stream>>>(Qb, Kb, Vb, mbits, Zb);
    // WO projection + residual 1 -> r (f32)
    gemm_nt<2><<<dim3(8, 64), blk, 0, stream>>>(Zb, wob, WO_b, x, rb, MROWS, DMODEL, DMODEL, 1.0f);
    // pre-LN of FFN
    ln_k<<<MROWS, 256, 0, stream>>>(rb, ln_g, ln_b, hln);
    // FFN
    gemm_nt<1><<<dim3(32, 64), blk, 0, stream>>>(hln,  w1b, W1_b, nullptr, hmid, MROWS, DFFN,   DMODEL, 1.0f);
    gemm_nt<2><<<dim3(8, 64),  blk, 0, stream>>>(hmid, w2b, W2_b, rb,      out,  MROWS, DMODEL, DFFN,   1.0f);
}

// Round 4
// 519.371 us; speedup vs baseline: 1.6019x; 1.0970x over previous
//
#include <hip/hip_runtime.h>

// Problem constants
#define BD      4
#define LSEQ    2048
#define DMODEL  1024
#define HHEADS  16
#define DKK     64
#define DFFN    4096
#define MROWS   (BD*LSEQ)   // 8192
#define QKVS    3072        // fused QKV row stride

typedef float  f32x4  __attribute__((ext_vector_type(4)));
typedef float  f32x16 __attribute__((ext_vector_type(16)));
typedef __bf16 bf16x8 __attribute__((ext_vector_type(8)));
typedef unsigned short u16x8 __attribute__((ext_vector_type(8)));
typedef unsigned int   u32x4 __attribute__((ext_vector_type(4)));

__device__ inline unsigned short f2bf(float x) {
    union { float f; unsigned u; } c; c.f = x;
    unsigned r = c.u + 0x7FFFu + ((c.u >> 16) & 1u);
    return (unsigned short)(r >> 16);
}

// ---------------- f32 -> bf16 cast ----------------
__global__ void cast_bf16_k(const float* __restrict__ in,
                            unsigned short* __restrict__ out, long n) {
    long i = ((long)blockIdx.x * blockDim.x + threadIdx.x) * 4;
    long stride = (long)gridDim.x * blockDim.x * 4;
    for (; i < n; i += stride) {
        float4 v = *(const float4*)(in + i);
        ushort4 o;
        o.x = f2bf(v.x); o.y = f2bf(v.y); o.z = f2bf(v.z); o.w = f2bf(v.w);
        *(ushort4*)(out + i) = o;
    }
}

// ---------------- mask -> bitmask ----------------
__global__ __launch_bounds__(256) void maskbits_k(const int* __restrict__ m,
                                                  unsigned long long* __restrict__ bits) {
    const long gw = ((long)blockIdx.x * blockDim.x + threadIdx.x) >> 6;
    const int lane = threadIdx.x & 63;
    const int b   = (int)(gw >> 16);
    const int rem = (int)gw & 65535;
    const int q = rem >> 5, kt = rem & 31;
    const int v = m[((size_t)(b*LSEQ + q))*LSEQ + kt*64 + lane];
    const unsigned long long bal = __ballot(v != 0);
    if (lane == 0) bits[((size_t)(b*32 + kt))*LSEQ + q] = bal;
}

// ---------------- async global->LDS 16B ----------------
__device__ inline void gload16(const void* g, void* l) {
    __builtin_amdgcn_global_load_lds(
        (const __attribute__((address_space(1))) void*)g,
        (__attribute__((address_space(3))) void*)l, 16, 0, 0);
}

// =================== 8-phase 256x256 NT GEMM (bf16) ===================
// C[M,N] = A[M,K]*B[N,K]^T; MODE 0: bf16 out, scale applied for col<1024
// (QKV: fold 1/8*log2(e) into Q). MODE 1: bf16 out + ReLU.
// 8 waves (2x4), BK=64, LDS 128KB double-buffered, T2 row-XOR swizzle,
// counted vmcnt (never 0 mid-loop), setprio around MFMA clusters.
#define BAR() { __builtin_amdgcn_sched_barrier(0); __builtin_amdgcn_s_barrier(); __builtin_amdgcn_sched_barrier(0); }

#define STAGE(XSEL, XPTR, h, tau, s)                                              \
  { const unsigned short* gs0 = (XPTR) + (size_t)((h)*128 + wid*8 + srow) * K + (tau)*64 + schk*8; \
    gload16(gs0, (void*)&sm[(s)][(XSEL)][(((h)*128 + wid*8)*64)]);                 \
    gload16(gs0 + (size_t)64*K, (void*)&sm[(s)][(XSEL)][(((h)*128 + 64 + wid*8)*64)]); }

#define LDA(dst, s, mi, kk) dst = *(const bf16x8*)(&sm[(s)][0][(wr*128 + (mi)*16 + r0)*64 + ((((kk)*4 + g) ^ (r0 & 7)) << 3)]);
#define LDB(dst, s, nj, kk) dst = *(const bf16x8*)(&sm[(s)][1][(wc*64  + (nj)*16 + r0)*64 + ((((kk)*4 + g) ^ (r0 & 7)) << 3)]);

#define PHASE_MFMA(q)                                                                                   \
    __builtin_amdgcn_s_setprio(1);                                                                      \
    _Pragma("unroll")                                                                                   \
    for (int nj = 0; nj < 4; ++nj) {                                                                    \
        acc[2*(q)][nj]   = __builtin_amdgcn_mfma_f32_16x16x32_bf16(af00, bq[nj][0], acc[2*(q)][nj],   0,0,0); \
        acc[2*(q)][nj]   = __builtin_amdgcn_mfma_f32_16x16x32_bf16(af01, bq[nj][1], acc[2*(q)][nj],   0,0,0); \
        acc[2*(q)+1][nj] = __builtin_amdgcn_mfma_f32_16x16x32_bf16(af10, bq[nj][0], acc[2*(q)+1][nj], 0,0,0); \
        acc[2*(q)+1][nj] = __builtin_amdgcn_mfma_f32_16x16x32_bf16(af11, bq[nj][1], acc[2*(q)+1][nj], 0,0,0); \
    }                                                                                                   \
    __builtin_amdgcn_s_setprio(0);

#define KTILE(s, tau)                                                        \
  {                                                                          \
    const int tp1 = (tau) + 1, tp2 = (tau) + 2;                              \
    bf16x8 bq[4][2];                                                         \
    bf16x8 af00, af01, af10, af11;                                           \
    /* phase 1: B all + A quad0; stage A0(tau+1) */                          \
    _Pragma("unroll") for (int nj = 0; nj < 4; ++nj) {                       \
        LDB(bq[nj][0], s, nj, 0); LDB(bq[nj][1], s, nj, 1); }                \
    LDA(af00, s, 0, 0); LDA(af01, s, 0, 1);                                  \
    LDA(af10, s, 1, 0); LDA(af11, s, 1, 1);                                  \
    if (tp1 < NTT) { STAGE(0, Ab, 0, tp1, (s)^1); }                          \
    BAR(); PHASE_MFMA(0); BAR();                                             \
    /* phase 2: A quad1; stage A1(tau+1), B0(tau+2) */                       \
    LDA(af00, s, 2, 0); LDA(af01, s, 2, 1);                                  \
    LDA(af10, s, 3, 0); LDA(af11, s, 3, 1);                                  \
    if (tp1 < NTT) { STAGE(0, Ab, 1, tp1, (s)^1); }                          \
    if (tp2 < NTT) { STAGE(1, Bb, 0, tp2, (s)); }                            \
    BAR(); PHASE_MFMA(1); BAR();                                             \
    /* phase 3: A quad2; stage B1(tau+2) */                                  \
    LDA(af00, s, 4, 0); LDA(af01, s, 4, 1);                                  \
    LDA(af10, s, 5, 0); LDA(af11, s, 5, 1);                                  \
    if (tp2 < NTT) { STAGE(1, Bb, 1, tp2, (s)); }                            \
    BAR(); PHASE_MFMA(2); BAR();                                             \
    /* phase 4: A quad3; counted vmcnt */                                    \
    LDA(af00, s, 6, 0); LDA(af01, s, 6, 1);                                  \
    LDA(af10, s, 7, 0); LDA(af11, s, 7, 1);                                  \
    if (tp2 < NTT)      { asm volatile("s_waitcnt vmcnt(4)" ::: "memory"); } \
    else if (tp1 < NTT) { asm volatile("s_waitcnt vmcnt(0)" ::: "memory"); } \
    BAR(); PHASE_MFMA(3); BAR();                                             \
  }

template<int MODE, int NTT>
__global__ __launch_bounds__(512, 2) void gemm8(const unsigned short* __restrict__ A,
                                                const unsigned short* __restrict__ B,
                                                const float* __restrict__ bias,
                                                unsigned short* __restrict__ Cout,
                                                int M, int N, int K, float scaleQ)
{
    __shared__ unsigned short sm[2][2][256*64];   // [slot][A/B][row*64+col] = 128 KiB
    const int t   = threadIdx.x;
    const int wid = t >> 6, lane = t & 63;
    const int wr  = wid >> 2, wc = wid & 3;
    const int r0  = lane & 15, g = lane >> 4;

    // bijective XCD swizzle (nwg % 8 == 0 for our shapes)
    const int nwg = gridDim.x;
    const int bid = (blockIdx.x & 7) * (nwg >> 3) + (blockIdx.x >> 3);
    const int ntn = N >> 8;
    const int bm  = (bid / ntn) << 8, bn = (bid % ntn) << 8;

    const int srow = lane >> 3;            // staging row-in-8
    const int schk = (lane & 7) ^ srow;    // swizzled source chunk
    const unsigned short* Ab = A + (size_t)bm * K;
    const unsigned short* Bb = B + (size_t)bn * K;

    f32x4 acc[8][4] = {};

    // prologue: stage tile0 (B,A) + tile1 (B); A(tile1) staged inside KTILE(0,0)
    STAGE(1, Bb, 0, 0, 0); STAGE(1, Bb, 1, 0, 0);
    STAGE(0, Ab, 0, 0, 0); STAGE(0, Ab, 1, 0, 0);
    STAGE(1, Bb, 0, 1, 1); STAGE(1, Bb, 1, 1, 1);
    asm volatile("s_waitcnt vmcnt(4)" ::: "memory");
    BAR();

#pragma unroll 1
    for (int i2 = 0; i2 < NTT/2; ++i2) {
        const int tau = 2*i2;
        KTILE(0, tau);
        KTILE(1, tau+1);
    }

    // epilogue
#pragma unroll
    for (int mi = 0; mi < 8; ++mi) {
        const int row0 = bm + wr*128 + mi*16 + g*4;
#pragma unroll
        for (int nj = 0; nj < 4; ++nj) {
            const int col = bn + wc*64 + nj*16 + r0;
            const float bcol = bias[col];
            const float sc = (MODE == 0) ? (col < 1024 ? scaleQ : 1.0f) : 1.0f;
#pragma unroll
            for (int rr = 0; rr < 4; ++rr) {
                float c = (acc[mi][nj][rr] + bcol) * sc;
                if (MODE == 1) c = fmaxf(c, 0.f);
                Cout[(size_t)(row0 + rr) * N + col] = f2bf(c);
            }
        }
    }
}

// ---------------- 128x128 NT GEMM (m97-structure) for WO / W2 ----------------
template<int MODE>
__global__ __launch_bounds__(256) void gemm_nt(const unsigned short* __restrict__ A,
                                               const unsigned short* __restrict__ B,
                                               const float* __restrict__ bias,
                                               const float* __restrict__ resid,
                                               void* __restrict__ Cout,
                                               int M, int N, int K, float scale)
{
    __shared__ unsigned short As[128*32];
    __shared__ unsigned short Bs[128*32];
    const int t    = threadIdx.x;
    const int w    = t >> 6, lane = t & 63;
    const int r0   = lane & 15, g = lane >> 4;
    const int wm   = (w >> 1) * 64, wn = (w & 1) * 64;
    const int bm   = blockIdx.y * 128, bn = blockIdx.x * 128;
    const int srow = t >> 2, scol = (t & 3) * 8;

    const unsigned short* Ag = A + (size_t)(bm + srow) * K + scol;
    const unsigned short* Bg = B + (size_t)(bn + srow) * K + scol;
    unsigned short* AsW = As + w * 512;
    unsigned short* BsW = Bs + w * 512;

    f32x4 acc[4][4] = {};

    for (int kt = 0; kt < K; kt += 32) {
        gload16(Ag + kt,                AsW);
        gload16(Ag + (size_t)64*K + kt, AsW + 2048);
        gload16(Bg + kt,                BsW);
        gload16(Bg + (size_t)64*K + kt, BsW + 2048);
        __syncthreads();
        bf16x8 af[4], bfr[4];
#pragma unroll
        for (int i = 0; i < 4; ++i)
            af[i] = *(const bf16x8*)(As + (wm + i*16 + r0)*32 + g*8);
#pragma unroll
        for (int j = 0; j < 4; ++j)
            bfr[j] = *(const bf16x8*)(Bs + (wn + j*16 + r0)*32 + g*8);
#pragma unroll
        for (int i = 0; i < 4; ++i)
#pragma unroll
            for (int j = 0; j < 4; ++j)
                acc[i][j] = __builtin_amdgcn_mfma_f32_16x16x32_bf16(af[i], bfr[j], acc[i][j], 0, 0, 0);
        __syncthreads();
    }

#pragma unroll
    for (int i = 0; i < 4; ++i) {
        const int row0 = bm + wm + i*16 + g*4;
#pragma unroll
        for (int j = 0; j < 4; ++j) {
            const int col = bn + wn + j*16 + r0;
            const float bcol = bias[col];
#pragma unroll
            for (int rr = 0; rr < 4; ++rr) {
                const int row = row0 + rr;
                float c = (acc[i][j][rr] + bcol) * scale;
                if (MODE == 2) {
                    ((float*)Cout)[(size_t)row * N + col] = c + resid[(size_t)row * N + col];
                } else {
                    if (MODE == 1) c = fmaxf(c, 0.f);
                    ((unsigned short*)Cout)[(size_t)row * N + col] = f2bf(c);
                }
            }
        }
    }
}

// ---------------- fused flash attention (log2-domain, fused QKV input) -------
#define MFILL   (-47272.79f)    /* -32767 * log2(e) */
#define DEFTHR  (11.5415603f)   /* 8 * log2(e) */
__global__ __launch_bounds__(256) void attn_k(
    const unsigned short* __restrict__ QKV,
    const unsigned long long* __restrict__ MBits,
    unsigned short* __restrict__ Z)
{
    __shared__ unsigned short Ks[2][64*64];
    __shared__ unsigned short Vt[64*64];
    __shared__ float Sc[4*32];

    const int t    = threadIdx.x;
    const int w    = t >> 6, lane = t & 63;
    const int q31  = lane & 31, hi = lane >> 5;

    const int bid = blockIdx.x;
    const int sw  = (bid & 7) * 128 + (bid >> 3);
    const int qt  = sw & 15, h = (sw >> 4) & 15, b = sw >> 8;
    const int qw  = qt * 128 + w * 32;

    const unsigned short* Qg = QKV + ((size_t)(b*LSEQ + qw + q31))*QKVS + h*DKK + hi*8;
    bf16x8 qf[4];
#pragma unroll
    for (int ds = 0; ds < 4; ++ds)
        qf[ds] = *(const bf16x8*)(Qg + ds*16);

    const int krow  = w*8 + (lane>>3);
    const int kchk  = (lane & 7) ^ (krow & 7);
    const unsigned short* Kg = QKV + ((size_t)(b*LSEQ))*QKVS + 1024 + h*DKK;
    const int kp   = w*8 + (lane>>3);
    const int vd0  = (lane & 7) * 8;
    const unsigned short* Vg = QKV + ((size_t)(b*LSEQ))*QKVS + 2048 + h*DKK + vd0;

    float m_r = MFILL, l_r = 0.f;
    f32x16 z0, z1;
#pragma unroll
    for (int r = 0; r < 16; ++r) { z0[r] = 0.f; z1[r] = 0.f; }

    // prologue: stage tile 0
    u16x8 vA = *(const u16x8*)(Vg + (size_t)(kp*2)*QKVS);
    u16x8 vB = *(const u16x8*)(Vg + (size_t)(kp*2+1)*QKVS);
#pragma unroll
    for (int i = 0; i < 8; ++i) {
        const int d = vd0 + i;
        const int c = (kp>>2) ^ (d&7) ^ (d>>3);
        *(unsigned*)&Vt[d*64 + c*8 + 2*(kp&3)] = (unsigned)vA[i] | ((unsigned)vB[i] << 16);
    }
    gload16(Kg + (size_t)krow*QKVS      + kchk*8, &Ks[0][w*512]);
    gload16(Kg + (size_t)(32+krow)*QKVS + kchk*8, &Ks[0][w*512] + 2048);

    for (int kt = 0; kt < LSEQ/64; ++kt) {
        const int cur = kt & 1;
        __syncthreads();

        if (kt < LSEQ/64 - 1) {
            const int k0n = (kt+1)*64;
            gload16(Kg + (size_t)(k0n + krow)*QKVS      + kchk*8, &Ks[cur^1][w*512]);
            gload16(Kg + (size_t)(k0n + 32 + krow)*QKVS + kchk*8, &Ks[cur^1][w*512] + 2048);
            vA = *(const u16x8*)(Vg + (size_t)(k0n + kp*2)*QKVS);
            vB = *(const u16x8*)(Vg + (size_t)(k0n + kp*2+1)*QKVS);
        }
        const unsigned long long mw = MBits[((size_t)(b*32 + kt))*LSEQ + (qw + q31)];
        const unsigned long long sh = mw >> (hi*4);
        const unsigned md0 = (unsigned)sh, md1 = (unsigned)(sh >> 32);

        f32x16 s0, s1;
#pragma unroll
        for (int r = 0; r < 16; ++r) { s0[r] = 0.f; s1[r] = 0.f; }
        __builtin_amdgcn_s_setprio(1);
#pragma unroll
        for (int ds = 0; ds < 4; ++ds) {
            const int slot = ((ds*2 + hi) ^ (q31 & 7)) << 3;
            bf16x8 kf0 = *(const bf16x8*)(&Ks[cur][ q31     *64 + slot]);
            bf16x8 kf1 = *(const bf16x8*)(&Ks[cur][(32+q31)*64 + slot]);
            s0 = __builtin_amdgcn_mfma_f32_32x32x16_bf16(kf0, qf[ds], s0, 0, 0, 0);
            s1 = __builtin_amdgcn_mfma_f32_32x32x16_bf16(kf1, qf[ds], s1, 0, 0, 0);
        }
        __builtin_amdgcn_s_setprio(0);

#pragma unroll
        for (int r = 0; r < 16; ++r) {
            const int kb = (r & 3) + 8*(r >> 2);
            if (!((md0 >> kb) & 1)) s0[r] = MFILL;
            if (!((md1 >> kb) & 1)) s1[r] = MFILL;
        }

        float tm = fmaxf(s0[0], s1[0]);
#pragma unroll
        for (int r = 1; r < 16; ++r) tm = fmaxf(tm, fmaxf(s0[r], s1[r]));
        {
            float ta = tm, tb = tm;
            asm volatile("v_permlane32_swap_b32 %0, %1" : "+v"(ta), "+v"(tb));
            tm = fmaxf(tm, hi ? ta : tb);
        }

        if (__any(tm > m_r + DEFTHR)) {
            const float nm   = fmaxf(m_r, tm);
            const float corr = exp2f(m_r - nm);
            Sc[w*32 + q31] = corr;
            l_r *= corr;
            m_r  = nm;
#pragma unroll
            for (int r = 0; r < 16; ++r) {
                const int row = (r & 3) + 8*(r >> 2) + 4*hi;
                const float cr = Sc[w*32 + row];
                z0[r] *= cr; z1[r] *= cr;
            }
        }

#pragma unroll
        for (int r = 0; r < 16; ++r) {
            s0[r] = exp2f(s0[r] - m_r);
            s1[r] = exp2f(s1[r] - m_r);
        }
        float r4[8];
#pragma unroll
        for (int r = 0; r < 8; ++r)
            r4[r] = (s0[2*r] + s0[2*r+1]) + (s1[2*r] + s1[2*r+1]);
        float rs = ((r4[0]+r4[1]) + (r4[2]+r4[3])) + ((r4[4]+r4[5]) + (r4[6]+r4[7]));
        {
            float ra = rs, rb = rs;
            asm volatile("v_permlane32_swap_b32 %0, %1" : "+v"(ra), "+v"(rb));
            rs += hi ? ra : rb;
        }
        l_r += rs;

        bf16x8 pa[4];
#pragma unroll
        for (int half = 0; half < 2; ++half) {
#pragma unroll
            for (int sub = 0; sub < 2; ++sub) {
                const int base = sub*8;
                unsigned wa, wb, wc, wd;
                float p0 = half ? s1[base+0] : s0[base+0];
                float p1 = half ? s1[base+1] : s0[base+1];
                float p2 = half ? s1[base+2] : s0[base+2];
                float p3 = half ? s1[base+3] : s0[base+3];
                float p4 = half ? s1[base+4] : s0[base+4];
                float p5 = half ? s1[base+5] : s0[base+5];
                float p6 = half ? s1[base+6] : s0[base+6];
                float p7 = half ? s1[base+7] : s0[base+7];
                asm("v_cvt_pk_bf16_f32 %0, %1, %2" : "=v"(wa) : "v"(p0), "v"(p1));
                asm("v_cvt_pk_bf16_f32 %0, %1, %2" : "=v"(wb) : "v"(p4), "v"(p5));
                asm("v_cvt_pk_bf16_f32 %0, %1, %2" : "=v"(wc) : "v"(p2), "v"(p3));
                asm("v_cvt_pk_bf16_f32 %0, %1, %2" : "=v"(wd) : "v"(p6), "v"(p7));
                asm volatile("v_permlane32_swap_b32 %0, %1" : "+v"(wa), "+v"(wb));
                asm volatile("v_permlane32_swap_b32 %0, %1" : "+v"(wc), "+v"(wd));
                u32x4 pu; pu[0] = wa; pu[1] = wc; pu[2] = wb; pu[3] = wd;
                pa[half*2 + sub] = __builtin_bit_cast(bf16x8, pu);
            }
        }

        __builtin_amdgcn_s_setprio(1);
#pragma unroll
        for (int ks = 0; ks < 4; ++ks) {
            const int ch = ks*2 + hi;
            bf16x8 vf0 = *(const bf16x8*)(&Vt[ q31     *64 + ((ch ^ (q31&7) ^ ( q31>>3)     ) << 3)]);
            bf16x8 vf1 = *(const bf16x8*)(&Vt[(32+q31)*64 + ((ch ^ (q31&7) ^ ((32+q31)>>3)) << 3)]);
            z0 = __builtin_amdgcn_mfma_f32_32x32x16_bf16(pa[ks], vf0, z0, 0, 0, 0);
            z1 = __builtin_amdgcn_mfma_f32_32x32x16_bf16(pa[ks], vf1, z1, 0, 0, 0);
        }
        __builtin_amdgcn_s_setprio(0);

        __syncthreads();

        if (kt < LSEQ/64 - 1) {
#pragma unroll
            for (int i = 0; i < 8; ++i) {
                const int d = vd0 + i;
                const int c = (kp>>2) ^ (d&7) ^ (d>>3);
                *(unsigned*)&Vt[d*64 + c*8 + 2*(kp&3)] = (unsigned)vA[i] | ((unsigned)vB[i] << 16);
            }
        }
    }

    Sc[w*32 + q31] = l_r;
    unsigned short* Zb = Z + ((size_t)(b*LSEQ + qw))*DMODEL + h*DKK + q31;
#pragma unroll
    for (int r = 0; r < 16; ++r) {
        const int row = (r & 3) + 8*(r >> 2) + 4*hi;
        const float rl = 1.0f / Sc[w*32 + row];
        Zb[(size_t)row*DMODEL]      = f2bf(z0[r] * rl);
        Zb[(size_t)row*DMODEL + 32] = f2bf(z1[r] * rl);
    }
}

// ---------------- LayerNorm (f32 in -> bf16 out) ----------------
__global__ __launch_bounds__(256) void ln_k(const float* __restrict__ r,
                                            const float* __restrict__ gam,
                                            const float* __restrict__ bet,
                                            unsigned short* __restrict__ out)
{
    const int row = blockIdx.x;
    const int t = threadIdx.x;
    const float* rp = r + (size_t)row * DMODEL;
    float4 v = *(const float4*)(rp + t*4);
    float s  = v.x + v.y + v.z + v.w;
    float s2 = v.x*v.x + v.y*v.y + v.z*v.z + v.w*v.w;
#pragma unroll
    for (int off = 32; off >= 1; off >>= 1) {
        s  += __shfl_xor(s,  off);
        s2 += __shfl_xor(s2, off);
    }
    __shared__ float red[8];
    const int wv = t >> 6;
    if ((t & 63) == 0) { red[wv] = s; red[4 + wv] = s2; }
    __syncthreads();
    s  = red[0] + red[1] + red[2] + red[3];
    s2 = red[4] + red[5] + red[6] + red[7];
    const float mu   = s  * (1.f/DMODEL);
    const float var  = s2 * (1.f/DMODEL) - mu*mu;
    const float rstd = rsqrtf(var + 1e-5f);
    float4 gv = *(const float4*)(gam + t*4);
    float4 bv = *(const float4*)(bet + t*4);
    ushort4 o;
    o.x = f2bf((v.x - mu)*rstd*gv.x + bv.x);
    o.y = f2bf((v.y - mu)*rstd*gv.y + bv.y);
    o.z = f2bf((v.z - mu)*rstd*gv.z + bv.z);
    o.w = f2bf((v.w - mu)*rstd*gv.w + bv.w);
    *(ushort4*)(out + (size_t)row * DMODEL + t*4) = o;
}

extern "C" void kernel_launch(void* const* d_in, const int* in_sizes, int n_in,
                              void* d_out, int out_size, void* d_ws, size_t ws_size,
                              hipStream_t stream)
{
    const float* x    = (const float*)d_in[0];
    const int*   mask = (const int*)  d_in[1];
    const float* WQ_w = (const float*)d_in[2];
    const float* WQ_b = (const float*)d_in[3];
    const float* WK_w = (const float*)d_in[4];
    const float* WK_b = (const float*)d_in[5];
    const float* WV_w = (const float*)d_in[6];
    const float* WV_b = (const float*)d_in[7];
    const float* WO_w = (const float*)d_in[8];
    const float* WO_b = (const float*)d_in[9];
    const float* ln_g = (const float*)d_in[10];
    const float* ln_b = (const float*)d_in[11];
    const float* W1_w = (const float*)d_in[12];
    const float* W1_b = (const float*)d_in[13];
    const float* W2_w = (const float*)d_in[14];
    const float* W2_b = (const float*)d_in[15];
    float* out = (float*)d_out;

    char* w = (char*)d_ws;
    const size_t MB = 1024*1024;
    unsigned short* qkv  = (unsigned short*)(w + 0*MB);    // 48MB fused QKV
    unsigned short* Zb   = (unsigned short*)(w + 48*MB);   // 16MB
    unsigned short* xb   = (unsigned short*)(w + 64*MB);   // 16MB
    float*          rb   = (float*)         (w + 80*MB);   // 32MB
    unsigned short* wqkv = (unsigned short*)(w + 112*MB);  // 6MB fused weights
    unsigned short* wob  = (unsigned short*)(w + 118*MB);  // 2MB
    unsigned short* w1b  = (unsigned short*)(w + 120*MB);  // 8MB
    unsigned short* w2b  = (unsigned short*)(w + 128*MB);  // 8MB
    unsigned long long* mbits = (unsigned long long*)(w + 136*MB); // 2MB
    float* bqkv = (float*)(w + 48*MB);   // 12KB, dead before attn writes Zb here
    unsigned short* hln  = xb;                            // xb dead after QKV
    unsigned short* hmid = (unsigned short*)(w + 0*MB);   // qkv+Zb dead after WO

    // casts + bitmask + fused bias concat
    cast_bf16_k<<<2048, 256, 0, stream>>>(x,    xb,   (long)MROWS*DMODEL);
    cast_bf16_k<<<512,  256, 0, stream>>>(WQ_w, wqkv,                 (long)DMODEL*DMODEL);
    cast_bf16_k<<<512,  256, 0, stream>>>(WK_w, wqkv + 1024*1024,     (long)DMODEL*DMODEL);
    cast_bf16_k<<<512,  256, 0, stream>>>(WV_w, wqkv + 2*1024*1024,   (long)DMODEL*DMODEL);
    cast_bf16_k<<<512,  256, 0, stream>>>(WO_w, wob,  (long)DMODEL*DMODEL);
    cast_bf16_k<<<2048, 256, 0, stream>>>(W1_w, w1b,  (long)DFFN*DMODEL);
    cast_bf16_k<<<2048, 256, 0, stream>>>(W2_w, w2b,  (long)DMODEL*DFFN);
    maskbits_k<<<65536, 256, 0, stream>>>(mask, mbits);
    hipMemcpyAsync(bqkv,        WQ_b, 1024*sizeof(float), hipMemcpyDeviceToDevice, stream);
    hipMemcpyAsync(bqkv + 1024, WK_b, 1024*sizeof(float), hipMemcpyDeviceToDevice, stream);
    hipMemcpyAsync(bqkv + 2048, WV_b, 1024*sizeof(float), hipMemcpyDeviceToDevice, stream);

    // fused QKV projection (Q scaled by 1/8 * log2(e): log2-domain softmax)
    gemm8<0, 16><<<dim3(384), dim3(512), 0, stream>>>(xb, wqkv, bqkv, qkv,
                                                      MROWS, QKVS, DMODEL, 0.18033688f);
    // fused attention
    attn_k<<<dim3(1024), dim3(256), 0, stream>>>(qkv, mbits, Zb);
    // WO projection + residual 1 -> r (f32)
    gemm_nt<2><<<dim3(8, 64), dim3(256), 0, stream>>>(Zb, wob, WO_b, x, rb, MROWS, DMODEL, DMODEL, 1.0f);
    // pre-LN of FFN
    ln_k<<<MROWS, 256, 0, stream>>>(rb, ln_g, ln_b, hln);
    // FFN
    gemm8<1, 16><<<dim3(512), dim3(512), 0, stream>>>(hln, w1b, W1_b, hmid,
                                                      MROWS, DFFN, DMODEL, 1.0f);
    gemm_nt<2><<<dim3(8, 64), dim3(256), 0, stream>>>(hmid, w2b, W2_b, rb, out, MROWS, DMODEL, DFFN, 1.0f);
}

// Round 5
// 508.237 us; speedup vs baseline: 1.6370x; 1.0219x over previous
//
#include <hip/hip_runtime.h>

// Problem constants
#define BD      4
#define LSEQ    2048
#define DMODEL  1024
#define HHEADS  16
#define DKK     64
#define DFFN    4096
#define MROWS   (BD*LSEQ)   // 8192
#define QKVS    3072        // fused QKV row stride

typedef float  f32x4  __attribute__((ext_vector_type(4)));
typedef float  f32x16 __attribute__((ext_vector_type(16)));
typedef __bf16 bf16x8 __attribute__((ext_vector_type(8)));
typedef unsigned short u16x8 __attribute__((ext_vector_type(8)));
typedef unsigned int   u32x4 __attribute__((ext_vector_type(4)));

__device__ inline unsigned short f2bf(float x) {
    union { float f; unsigned u; } c; c.f = x;
    unsigned r = c.u + 0x7FFFu + ((c.u >> 16) & 1u);
    return (unsigned short)(r >> 16);
}

// ---------------- f32 -> bf16 cast ----------------
__global__ void cast_bf16_k(const float* __restrict__ in,
                            unsigned short* __restrict__ out, long n) {
    long i = ((long)blockIdx.x * blockDim.x + threadIdx.x) * 4;
    long stride = (long)gridDim.x * blockDim.x * 4;
    for (; i < n; i += stride) {
        float4 v = *(const float4*)(in + i);
        ushort4 o;
        o.x = f2bf(v.x); o.y = f2bf(v.y); o.z = f2bf(v.z); o.w = f2bf(v.w);
        *(ushort4*)(out + i) = o;
    }
}

// ---------------- bias concat (Q|K|V) ----------------
__global__ void concat3_k(const float* __restrict__ a, const float* __restrict__ b,
                          const float* __restrict__ c, float* __restrict__ o) {
    int i = blockIdx.x * 256 + threadIdx.x;
    if (i < 1024) { o[i] = a[i]; o[1024 + i] = b[i]; o[2048 + i] = c[i]; }
}

// ---------------- mask -> bitmask ----------------
__global__ __launch_bounds__(256) void maskbits_k(const int* __restrict__ m,
                                                  unsigned long long* __restrict__ bits) {
    const long gw = ((long)blockIdx.x * blockDim.x + threadIdx.x) >> 6;
    const int lane = threadIdx.x & 63;
    const int b   = (int)(gw >> 16);
    const int rem = (int)gw & 65535;
    const int q = rem >> 5, kt = rem & 31;
    const int v = m[((size_t)(b*LSEQ + q))*LSEQ + kt*64 + lane];
    const unsigned long long bal = __ballot(v != 0);
    if (lane == 0) bits[((size_t)(b*32 + kt))*LSEQ + q] = bal;
}

// ---------------- async global->LDS 16B ----------------
__device__ inline void gload16(const void* g, void* l) {
    __builtin_amdgcn_global_load_lds(
        (const __attribute__((address_space(1))) void*)g,
        (__attribute__((address_space(3))) void*)l, 16, 0, 0);
}

#define BAR() { __builtin_amdgcn_sched_barrier(0); __builtin_amdgcn_s_barrier(); __builtin_amdgcn_sched_barrier(0); }

// =================== 8-phase 256x256 NT GEMM (bf16) ===================
#define STAGE(XSEL, XPTR, h, tau, s)                                              \
  { const unsigned short* gs0 = (XPTR) + (size_t)((h)*128 + wid*8 + srow) * K + (tau)*64 + schk*8; \
    gload16(gs0, (void*)&sm[(s)][(XSEL)][(((h)*128 + wid*8)*64)]);                 \
    gload16(gs0 + (size_t)64*K, (void*)&sm[(s)][(XSEL)][(((h)*128 + 64 + wid*8)*64)]); }

#define LDA(dst, s, mi, kk) dst = *(const bf16x8*)(&sm[(s)][0][(wr*128 + (mi)*16 + r0)*64 + ((((kk)*4 + g) ^ (r0 & 7)) << 3)]);
#define LDB(dst, s, nj, kk) dst = *(const bf16x8*)(&sm[(s)][1][(wc*64  + (nj)*16 + r0)*64 + ((((kk)*4 + g) ^ (r0 & 7)) << 3)]);

#define PHASE_MFMA(q)                                                                                   \
    __builtin_amdgcn_s_setprio(1);                                                                      \
    _Pragma("unroll")                                                                                   \
    for (int nj = 0; nj < 4; ++nj) {                                                                    \
        acc[2*(q)][nj]   = __builtin_amdgcn_mfma_f32_16x16x32_bf16(af00, bq[nj][0], acc[2*(q)][nj],   0,0,0); \
        acc[2*(q)][nj]   = __builtin_amdgcn_mfma_f32_16x16x32_bf16(af01, bq[nj][1], acc[2*(q)][nj],   0,0,0); \
        acc[2*(q)+1][nj] = __builtin_amdgcn_mfma_f32_16x16x32_bf16(af10, bq[nj][0], acc[2*(q)+1][nj], 0,0,0); \
        acc[2*(q)+1][nj] = __builtin_amdgcn_mfma_f32_16x16x32_bf16(af11, bq[nj][1], acc[2*(q)+1][nj], 0,0,0); \
    }                                                                                                   \
    __builtin_amdgcn_s_setprio(0);

#define KTILE(s, tau)                                                        \
  {                                                                          \
    const int tp1 = (tau) + 1, tp2 = (tau) + 2;                              \
    bf16x8 bq[4][2];                                                         \
    bf16x8 af00, af01, af10, af11;                                           \
    _Pragma("unroll") for (int nj = 0; nj < 4; ++nj) {                       \
        LDB(bq[nj][0], s, nj, 0); LDB(bq[nj][1], s, nj, 1); }                \
    LDA(af00, s, 0, 0); LDA(af01, s, 0, 1);                                  \
    LDA(af10, s, 1, 0); LDA(af11, s, 1, 1);                                  \
    if (tp1 < NTT) { STAGE(0, Ab, 0, tp1, (s)^1); }                          \
    BAR(); PHASE_MFMA(0); BAR();                                             \
    LDA(af00, s, 2, 0); LDA(af01, s, 2, 1);                                  \
    LDA(af10, s, 3, 0); LDA(af11, s, 3, 1);                                  \
    if (tp1 < NTT) { STAGE(0, Ab, 1, tp1, (s)^1); }                          \
    if (tp2 < NTT) { STAGE(1, Bb, 0, tp2, (s)); }                            \
    BAR(); PHASE_MFMA(1); BAR();                                             \
    LDA(af00, s, 4, 0); LDA(af01, s, 4, 1);                                  \
    LDA(af10, s, 5, 0); LDA(af11, s, 5, 1);                                  \
    if (tp2 < NTT) { STAGE(1, Bb, 1, tp2, (s)); }                            \
    BAR(); PHASE_MFMA(2); BAR();                                             \
    LDA(af00, s, 6, 0); LDA(af01, s, 6, 1);                                  \
    LDA(af10, s, 7, 0); LDA(af11, s, 7, 1);                                  \
    if (tp2 < NTT)      { asm volatile("s_waitcnt vmcnt(4)" ::: "memory"); } \
    else if (tp1 < NTT) { asm volatile("s_waitcnt vmcnt(0)" ::: "memory"); } \
    BAR(); PHASE_MFMA(3); BAR();                                             \
  }

template<int MODE, int NTT>
__global__ __launch_bounds__(512, 1) void gemm8(const unsigned short* __restrict__ A,
                                                const unsigned short* __restrict__ B,
                                                const float* __restrict__ bias,
                                                unsigned short* __restrict__ Cout,
                                                int M, int N, int K, float scaleQ)
{
    __shared__ unsigned short sm[2][2][256*64];
    const int t   = threadIdx.x;
    const int wid = t >> 6, lane = t & 63;
    const int wr  = wid >> 2, wc = wid & 3;
    const int r0  = lane & 15, g = lane >> 4;

    const int nwg = gridDim.x;
    const int bid = (blockIdx.x & 7) * (nwg >> 3) + (blockIdx.x >> 3);
    const int ntn = N >> 8;
    const int bm  = (bid / ntn) << 8, bn = (bid % ntn) << 8;

    const int srow = lane >> 3;
    const int schk = (lane & 7) ^ srow;
    const unsigned short* Ab = A + (size_t)bm * K;
    const unsigned short* Bb = B + (size_t)bn * K;

    f32x4 acc[8][4] = {};

    STAGE(1, Bb, 0, 0, 0); STAGE(1, Bb, 1, 0, 0);
    STAGE(0, Ab, 0, 0, 0); STAGE(0, Ab, 1, 0, 0);
    STAGE(1, Bb, 0, 1, 1); STAGE(1, Bb, 1, 1, 1);
    asm volatile("s_waitcnt vmcnt(4)" ::: "memory");
    BAR();

#pragma unroll 1
    for (int i2 = 0; i2 < NTT/2; ++i2) {
        const int tau = 2*i2;
        KTILE(0, tau);
        KTILE(1, tau+1);
    }

#pragma unroll
    for (int mi = 0; mi < 8; ++mi) {
        const int row0 = bm + wr*128 + mi*16 + g*4;
#pragma unroll
        for (int nj = 0; nj < 4; ++nj) {
            const int col = bn + wc*64 + nj*16 + r0;
            const float bcol = bias[col];
            const float sc = (MODE == 0) ? (col < 1024 ? scaleQ : 1.0f) : 1.0f;
#pragma unroll
            for (int rr = 0; rr < 4; ++rr) {
                float c = (acc[mi][nj][rr] + bcol) * sc;
                if (MODE == 1) c = fmaxf(c, 0.f);
                Cout[(size_t)(row0 + rr) * N + col] = f2bf(c);
            }
        }
    }
}

// =================== 8-phase 256x128 NT GEMM variant ===================
// BM=256, BN=128, 8 waves (2x4), wave tile 128x32. MODE 0: bf16 out with
// scaleQ for col<1024. MODE 2: f32 out + residual.
#define STAGEA2(h, tau, s)                                                        \
  { const unsigned short* gs0 = Ab + (size_t)((h)*128 + wid*8 + srow) * K + (tau)*64 + schk*8; \
    gload16(gs0, (void*)&smA[(s)][(((h)*128 + wid*8)*64)]);                        \
    gload16(gs0 + (size_t)64*K, (void*)&smA[(s)][(((h)*128 + 64 + wid*8)*64)]); }

#define STAGEB2(tau, s)                                                           \
  { const unsigned short* gs0 = Bb + (size_t)(wid*8 + srow) * K + (tau)*64 + schk*8; \
    gload16(gs0, (void*)&smB[(s)][((wid*8)*64)]);                                  \
    gload16(gs0 + (size_t)64*K, (void*)&smB[(s)][((64 + wid*8)*64)]); }

#define LDA2(dst, s, mi, kk) dst = *(const bf16x8*)(&smA[(s)][(wr*128 + (mi)*16 + r0)*64 + ((((kk)*4 + g) ^ (r0 & 7)) << 3)]);
#define LDB2(dst, s, nj, kk) dst = *(const bf16x8*)(&smB[(s)][(wc*32  + (nj)*16 + r0)*64 + ((((kk)*4 + g) ^ (r0 & 7)) << 3)]);

#define PHASE_MFMA2(q)                                                                                  \
    __builtin_amdgcn_s_setprio(1);                                                                      \
    _Pragma("unroll")                                                                                   \
    for (int nj = 0; nj < 2; ++nj) {                                                                    \
        acc[2*(q)][nj]   = __builtin_amdgcn_mfma_f32_16x16x32_bf16(af00, bq[nj][0], acc[2*(q)][nj],   0,0,0); \
        acc[2*(q)][nj]   = __builtin_amdgcn_mfma_f32_16x16x32_bf16(af01, bq[nj][1], acc[2*(q)][nj],   0,0,0); \
        acc[2*(q)+1][nj] = __builtin_amdgcn_mfma_f32_16x16x32_bf16(af10, bq[nj][0], acc[2*(q)+1][nj], 0,0,0); \
        acc[2*(q)+1][nj] = __builtin_amdgcn_mfma_f32_16x16x32_bf16(af11, bq[nj][1], acc[2*(q)+1][nj], 0,0,0); \
    }                                                                                                   \
    __builtin_amdgcn_s_setprio(0);

#define KTILE2(s, tau)                                                       \
  {                                                                          \
    const int tp1 = (tau) + 1, tp2 = (tau) + 2;                              \
    bf16x8 bq[2][2];                                                         \
    bf16x8 af00, af01, af10, af11;                                           \
    _Pragma("unroll") for (int nj = 0; nj < 2; ++nj) {                       \
        LDB2(bq[nj][0], s, nj, 0); LDB2(bq[nj][1], s, nj, 1); }              \
    LDA2(af00, s, 0, 0); LDA2(af01, s, 0, 1);                                \
    LDA2(af10, s, 1, 0); LDA2(af11, s, 1, 1);                                \
    if (tp1 < NTT) { STAGEA2(0, tp1, (s)^1); }                               \
    BAR(); PHASE_MFMA2(0); BAR();                                            \
    LDA2(af00, s, 2, 0); LDA2(af01, s, 2, 1);                                \
    LDA2(af10, s, 3, 0); LDA2(af11, s, 3, 1);                                \
    if (tp1 < NTT) { STAGEA2(1, tp1, (s)^1); }                               \
    BAR(); PHASE_MFMA2(1); BAR();                                            \
    LDA2(af00, s, 4, 0); LDA2(af01, s, 4, 1);                                \
    LDA2(af10, s, 5, 0); LDA2(af11, s, 5, 1);                                \
    if (tp2 < NTT) { STAGEB2(tp2, (s)); }                                    \
    BAR(); PHASE_MFMA2(2); BAR();                                            \
    LDA2(af00, s, 6, 0); LDA2(af01, s, 6, 1);                                \
    LDA2(af10, s, 7, 0); LDA2(af11, s, 7, 1);                                \
    if (tp2 < NTT)      { asm volatile("s_waitcnt vmcnt(2)" ::: "memory"); } \
    else if (tp1 < NTT) { asm volatile("s_waitcnt vmcnt(0)" ::: "memory"); } \
    BAR(); PHASE_MFMA2(3); BAR();                                            \
  }

template<int MODE, int NTT>
__global__ __launch_bounds__(512, 1) void gemm8n(const unsigned short* __restrict__ A,
                                                 const unsigned short* __restrict__ B,
                                                 const float* __restrict__ bias,
                                                 const float* __restrict__ resid,
                                                 void* __restrict__ Cout,
                                                 int M, int N, int K, float scaleQ)
{
    __shared__ unsigned short smA[2][256*64];   // 64 KiB
    __shared__ unsigned short smB[2][128*64];   // 32 KiB
    const int t   = threadIdx.x;
    const int wid = t >> 6, lane = t & 63;
    const int wr  = wid >> 2, wc = wid & 3;
    const int r0  = lane & 15, g = lane >> 4;

    const int nwg = gridDim.x;
    const int bid = (blockIdx.x & 7) * (nwg >> 3) + (blockIdx.x >> 3);
    const int ntn = N >> 7;
    const int bm  = (bid / ntn) << 8, bn = (bid % ntn) << 7;

    const int srow = lane >> 3;
    const int schk = (lane & 7) ^ srow;
    const unsigned short* Ab = A + (size_t)bm * K;
    const unsigned short* Bb = B + (size_t)bn * K;

    f32x4 acc[8][2] = {};

    STAGEB2(0, 0);
    STAGEA2(0, 0, 0); STAGEA2(1, 0, 0);
    STAGEB2(1, 1);
    asm volatile("s_waitcnt vmcnt(2)" ::: "memory");
    BAR();

#pragma unroll 1
    for (int i2 = 0; i2 < NTT/2; ++i2) {
        const int tau = 2*i2;
        KTILE2(0, tau);
        KTILE2(1, tau+1);
    }

#pragma unroll
    for (int mi = 0; mi < 8; ++mi) {
        const int row0 = bm + wr*128 + mi*16 + g*4;
#pragma unroll
        for (int nj = 0; nj < 2; ++nj) {
            const int col = bn + wc*32 + nj*16 + r0;
            const float bcol = bias[col];
            const float sc = (MODE == 0) ? (col < 1024 ? scaleQ : 1.0f) : 1.0f;
#pragma unroll
            for (int rr = 0; rr < 4; ++rr) {
                const int row = row0 + rr;
                float c = (acc[mi][nj][rr] + bcol) * sc;
                if (MODE == 2) {
                    ((float*)Cout)[(size_t)row * N + col] = c + resid[(size_t)row * N + col];
                } else {
                    ((unsigned short*)Cout)[(size_t)row * N + col] = f2bf(c);
                }
            }
        }
    }
}

// ---------------- 128x128 NT GEMM (m97-structure) for WO ----------------
template<int MODE>
__global__ __launch_bounds__(256) void gemm_nt(const unsigned short* __restrict__ A,
                                               const unsigned short* __restrict__ B,
                                               const float* __restrict__ bias,
                                               const float* __restrict__ resid,
                                               void* __restrict__ Cout,
                                               int M, int N, int K, float scale)
{
    __shared__ unsigned short As[128*32];
    __shared__ unsigned short Bs[128*32];
    const int t    = threadIdx.x;
    const int w    = t >> 6, lane = t & 63;
    const int r0   = lane & 15, g = lane >> 4;
    const int wm   = (w >> 1) * 64, wn = (w & 1) * 64;
    const int bm   = blockIdx.y * 128, bn = blockIdx.x * 128;
    const int srow = t >> 2, scol = (t & 3) * 8;

    const unsigned short* Ag = A + (size_t)(bm + srow) * K + scol;
    const unsigned short* Bg = B + (size_t)(bn + srow) * K + scol;
    unsigned short* AsW = As + w * 512;
    unsigned short* BsW = Bs + w * 512;

    f32x4 acc[4][4] = {};

    for (int kt = 0; kt < K; kt += 32) {
        gload16(Ag + kt,                AsW);
        gload16(Ag + (size_t)64*K + kt, AsW + 2048);
        gload16(Bg + kt,                BsW);
        gload16(Bg + (size_t)64*K + kt, BsW + 2048);
        __syncthreads();
        bf16x8 af[4], bfr[4];
#pragma unroll
        for (int i = 0; i < 4; ++i)
            af[i] = *(const bf16x8*)(As + (wm + i*16 + r0)*32 + g*8);
#pragma unroll
        for (int j = 0; j < 4; ++j)
            bfr[j] = *(const bf16x8*)(Bs + (wn + j*16 + r0)*32 + g*8);
#pragma unroll
        for (int i = 0; i < 4; ++i)
#pragma unroll
            for (int j = 0; j < 4; ++j)
                acc[i][j] = __builtin_amdgcn_mfma_f32_16x16x32_bf16(af[i], bfr[j], acc[i][j], 0, 0, 0);
        __syncthreads();
    }

#pragma unroll
    for (int i = 0; i < 4; ++i) {
        const int row0 = bm + wm + i*16 + g*4;
#pragma unroll
        for (int j = 0; j < 4; ++j) {
            const int col = bn + wn + j*16 + r0;
            const float bcol = bias[col];
#pragma unroll
            for (int rr = 0; rr < 4; ++rr) {
                const int row = row0 + rr;
                float c = (acc[i][j][rr] + bcol) * scale;
                if (MODE == 2) {
                    ((float*)Cout)[(size_t)row * N + col] = c + resid[(size_t)row * N + col];
                } else {
                    if (MODE == 1) c = fmaxf(c, 0.f);
                    ((unsigned short*)Cout)[(size_t)row * N + col] = f2bf(c);
                }
            }
        }
    }
}

// ---------------- fused flash attention ----------------
// log2-domain softmax; Q in swizzled LDS; K via gload_lds (src-swizzled,
// double-buffered); V^T reg-staged (double-buffered); mask word prefetched;
// ONE barrier per tile.
#define MFILL   (-47272.79f)    /* -32767 * log2(e) */
#define DEFTHR  (11.5415603f)   /* 8 * log2(e) */
__global__ __launch_bounds__(256) void attn_k(
    const unsigned short* __restrict__ QKV,
    const unsigned long long* __restrict__ MBits,
    unsigned short* __restrict__ Z)
{
    __shared__ unsigned short Ks[2][64*64];   // 16 KB
    __shared__ unsigned short Vt[2][64*64];   // 16 KB
    __shared__ unsigned short Qs[128*64];     // 16 KB
    __shared__ float Sc[4*32];

    const int t    = threadIdx.x;
    const int w    = t >> 6, lane = t & 63;
    const int q31  = lane & 31, hi = lane >> 5;

    const int bid = blockIdx.x;
    const int sw  = (bid & 7) * 128 + (bid >> 3);
    const int qt  = sw & 15, h = (sw >> 4) & 15, b = sw >> 8;
    const int qw  = qt * 128 + w * 32;

    // ---- stage Q tile (128 rows) into swizzled LDS ----
    {
        const int qrow = t & 127;
        const int cb   = (t >> 7) * 4;
        const unsigned short* Qgs = QKV + ((size_t)(b*LSEQ + qt*128 + qrow))*QKVS + h*DKK;
#pragma unroll
        for (int j = 0; j < 4; ++j) {
            u16x8 qv = *(const u16x8*)(Qgs + (cb + j)*8);
            *(u16x8*)&Qs[qrow*64 + (((cb + j) ^ (qrow & 7)) << 3)] = qv;
        }
    }

    const int krow  = w*8 + (lane>>3);
    const int kchk  = (lane & 7) ^ (krow & 7);
    const unsigned short* Kg = QKV + ((size_t)(b*LSEQ))*QKVS + 1024 + h*DKK;
    const int kp   = w*8 + (lane>>3);
    const int vd0  = (lane & 7) * 8;
    const unsigned short* Vg = QKV + ((size_t)(b*LSEQ))*QKVS + 2048 + h*DKK + vd0;
    const unsigned short* Qrow = &Qs[(w*32 + q31)*64];

    float m_r = MFILL, l_r = 0.f;
    f32x16 z0, z1;
#pragma unroll
    for (int r = 0; r < 16; ++r) { z0[r] = 0.f; z1[r] = 0.f; }

    // ---- prologue: stage tile 0 (V^T regs->LDS, K gload) + mask word ----
    {
        u16x8 vA = *(const u16x8*)(Vg + (size_t)(kp*2)*QKVS);
        u16x8 vB = *(const u16x8*)(Vg + (size_t)(kp*2+1)*QKVS);
#pragma unroll
        for (int i = 0; i < 8; ++i) {
            const int d = vd0 + i;
            const int c = (kp>>2) ^ (d&7) ^ (d>>3);
            *(unsigned*)&Vt[0][d*64 + c*8 + 2*(kp&3)] = (unsigned)vA[i] | ((unsigned)vB[i] << 16);
        }
    }
    gload16(Kg + (size_t)krow*QKVS      + kchk*8, &Ks[0][w*512]);
    gload16(Kg + (size_t)(32+krow)*QKVS + kchk*8, &Ks[0][w*512] + 2048);
    unsigned long long mw = MBits[((size_t)(b*32 + 0))*LSEQ + (qw + q31)];

    __syncthreads();   // Qs, Ks[0], Vt[0] ready

    for (int kt = 0; kt < LSEQ/64; ++kt) {
        const int cur = kt & 1;
        const int ktn = (kt < LSEQ/64 - 1) ? kt + 1 : kt;
        const int k0n = ktn * 64;

        // early-issue next tile's loads + mask word
        gload16(Kg + (size_t)(k0n + krow)*QKVS      + kchk*8, &Ks[cur^1][w*512]);
        gload16(Kg + (size_t)(k0n + 32 + krow)*QKVS + kchk*8, &Ks[cur^1][w*512] + 2048);
        u16x8 vA = *(const u16x8*)(Vg + (size_t)(k0n + kp*2)*QKVS);
        u16x8 vB = *(const u16x8*)(Vg + (size_t)(k0n + kp*2+1)*QKVS);
        const unsigned long long mwn = MBits[((size_t)(b*32 + ktn))*LSEQ + (qw + q31)];

        const unsigned long long sh = mw >> (hi*4);
        const unsigned md0 = (unsigned)sh, md1 = (unsigned)(sh >> 32);

        // ---- QK^T (swapped): s = K_tile * Q^T ----
        f32x16 s0, s1;
#pragma unroll
        for (int r = 0; r < 16; ++r) { s0[r] = 0.f; s1[r] = 0.f; }
        __builtin_amdgcn_s_setprio(1);
#pragma unroll
        for (int ds = 0; ds < 4; ++ds) {
            const int slot = ((ds*2 + hi) ^ (q31 & 7)) << 3;
            bf16x8 kf0 = *(const bf16x8*)(&Ks[cur][ q31     *64 + slot]);
            bf16x8 kf1 = *(const bf16x8*)(&Ks[cur][(32+q31)*64 + slot]);
            bf16x8 qf  = *(const bf16x8*)(Qrow + slot);
            s0 = __builtin_amdgcn_mfma_f32_32x32x16_bf16(kf0, qf, s0, 0, 0, 0);
            s1 = __builtin_amdgcn_mfma_f32_32x32x16_bf16(kf1, qf, s1, 0, 0, 0);
        }
        __builtin_amdgcn_s_setprio(0);

        // ---- mask fill ----
#pragma unroll
        for (int r = 0; r < 16; ++r) {
            const int kb = (r & 3) + 8*(r >> 2);
            if (!((md0 >> kb) & 1)) s0[r] = MFILL;
            if (!((md1 >> kb) & 1)) s1[r] = MFILL;
        }

        // ---- row max ----
        float tm = fmaxf(s0[0], s1[0]);
#pragma unroll
        for (int r = 1; r < 16; ++r) tm = fmaxf(tm, fmaxf(s0[r], s1[r]));
        {
            float ta = tm, tb = tm;
            asm volatile("v_permlane32_swap_b32 %0, %1" : "+v"(ta), "+v"(tb));
            tm = fmaxf(tm, hi ? ta : tb);
        }

        // ---- defer-max rescale (rare) ----
        if (__any(tm > m_r + DEFTHR)) {
            const float nm   = fmaxf(m_r, tm);
            const float corr = exp2f(m_r - nm);
            Sc[w*32 + q31] = corr;
            l_r *= corr;
            m_r  = nm;
#pragma unroll
            for (int r = 0; r < 16; ++r) {
                const int row = (r & 3) + 8*(r >> 2) + 4*hi;
                const float cr = Sc[w*32 + row];
                z0[r] *= cr; z1[r] *= cr;
            }
        }

        // ---- exp (log2 domain) ----
#pragma unroll
        for (int r = 0; r < 16; ++r) {
            s0[r] = exp2f(s0[r] - m_r);
            s1[r] = exp2f(s1[r] - m_r);
        }
        // ---- row sum ----
        float r4[8];
#pragma unroll
        for (int r = 0; r < 8; ++r)
            r4[r] = (s0[2*r] + s0[2*r+1]) + (s1[2*r] + s1[2*r+1]);
        float rs = ((r4[0]+r4[1]) + (r4[2]+r4[3])) + ((r4[4]+r4[5]) + (r4[6]+r4[7]));
        {
            float ra = rs, rb = rs;
            asm volatile("v_permlane32_swap_b32 %0, %1" : "+v"(ra), "+v"(rb));
            rs += hi ? ra : rb;
        }
        l_r += rs;

        // ---- P->bf16 A-frag per ks (transient) + PV MFMA ----
        __builtin_amdgcn_s_setprio(1);
#pragma unroll
        for (int half = 0; half < 2; ++half) {
#pragma unroll
            for (int sub = 0; sub < 2; ++sub) {
                const int base = sub*8;
                unsigned wa, wb, wc2, wd;
                float p0 = half ? s1[base+0] : s0[base+0];
                float p1 = half ? s1[base+1] : s0[base+1];
                float p2 = half ? s1[base+2] : s0[base+2];
                float p3 = half ? s1[base+3] : s0[base+3];
                float p4 = half ? s1[base+4] : s0[base+4];
                float p5 = half ? s1[base+5] : s0[base+5];
                float p6 = half ? s1[base+6] : s0[base+6];
                float p7 = half ? s1[base+7] : s0[base+7];
                asm("v_cvt_pk_bf16_f32 %0, %1, %2" : "=v"(wa) : "v"(p0), "v"(p1));
                asm("v_cvt_pk_bf16_f32 %0, %1, %2" : "=v"(wb) : "v"(p4), "v"(p5));
                asm("v_cvt_pk_bf16_f32 %0, %1, %2" : "=v"(wc2) : "v"(p2), "v"(p3));
                asm("v_cvt_pk_bf16_f32 %0, %1, %2" : "=v"(wd) : "v"(p6), "v"(p7));
                asm volatile("v_permlane32_swap_b32 %0, %1" : "+v"(wa), "+v"(wb));
                asm volatile("v_permlane32_swap_b32 %0, %1" : "+v"(wc2), "+v"(wd));
                u32x4 pu; pu[0] = wa; pu[1] = wc2; pu[2] = wb; pu[3] = wd;
                bf16x8 pa = __builtin_bit_cast(bf16x8, pu);
                const int ks = half*2 + sub;
                const int ch = ks*2 + hi;
                bf16x8 vf0 = *(const bf16x8*)(&Vt[cur][ q31     *64 + ((ch ^ (q31&7) ^ ( q31>>3)     ) << 3)]);
                bf16x8 vf1 = *(const bf16x8*)(&Vt[cur][(32+q31)*64 + ((ch ^ (q31&7) ^ ((32+q31)>>3)) << 3)]);
                z0 = __builtin_amdgcn_mfma_f32_32x32x16_bf16(pa, vf0, z0, 0, 0, 0);
                z1 = __builtin_amdgcn_mfma_f32_32x32x16_bf16(pa, vf1, z1, 0, 0, 0);
            }
        }
        __builtin_amdgcn_s_setprio(0);

        // ---- write next tile's V^T into other buffer ----
#pragma unroll
        for (int i = 0; i < 8; ++i) {
            const int d = vd0 + i;
            const int c = (kp>>2) ^ (d&7) ^ (d>>3);
            *(unsigned*)&Vt[cur^1][d*64 + c*8 + 2*(kp&3)] = (unsigned)vA[i] | ((unsigned)vB[i] << 16);
        }
        mw = mwn;
        __syncthreads();   // single barrier per tile
    }

    // ---- epilogue ----
    Sc[w*32 + q31] = l_r;
    unsigned short* Zb = Z + ((size_t)(b*LSEQ + qw))*DMODEL + h*DKK + q31;
#pragma unroll
    for (int r = 0; r < 16; ++r) {
        const int row = (r & 3) + 8*(r >> 2) + 4*hi;
        const float rl = 1.0f / Sc[w*32 + row];
        Zb[(size_t)row*DMODEL]      = f2bf(z0[r] * rl);
        Zb[(size_t)row*DMODEL + 32] = f2bf(z1[r] * rl);
    }
}

// ---------------- LayerNorm (f32 in -> bf16 out) ----------------
__global__ __launch_bounds__(256) void ln_k(const float* __restrict__ r,
                                            const float* __restrict__ gam,
                                            const float* __restrict__ bet,
                                            unsigned short* __restrict__ out)
{
    const int row = blockIdx.x;
    const int t = threadIdx.x;
    const float* rp = r + (size_t)row * DMODEL;
    float4 v = *(const float4*)(rp + t*4);
    float s  = v.x + v.y + v.z + v.w;
    float s2 = v.x*v.x + v.y*v.y + v.z*v.z + v.w*v.w;
#pragma unroll
    for (int off = 32; off >= 1; off >>= 1) {
        s  += __shfl_xor(s,  off);
        s2 += __shfl_xor(s2, off);
    }
    __shared__ float red[8];
    const int wv = t >> 6;
    if ((t & 63) == 0) { red[wv] = s; red[4 + wv] = s2; }
    __syncthreads();
    s  = red[0] + red[1] + red[2] + red[3];
    s2 = red[4] + red[5] + red[6] + red[7];
    const float mu   = s  * (1.f/DMODEL);
    const float var  = s2 * (1.f/DMODEL) - mu*mu;
    const float rstd = rsqrtf(var + 1e-5f);
    float4 gv = *(const float4*)(gam + t*4);
    float4 bv = *(const float4*)(bet + t*4);
    ushort4 o;
    o.x = f2bf((v.x - mu)*rstd*gv.x + bv.x);
    o.y = f2bf((v.y - mu)*rstd*gv.y + bv.y);
    o.z = f2bf((v.z - mu)*rstd*gv.z + bv.z);
    o.w = f2bf((v.w - mu)*rstd*gv.w + bv.w);
    *(ushort4*)(out + (size_t)row * DMODEL + t*4) = o;
}

extern "C" void kernel_launch(void* const* d_in, const int* in_sizes, int n_in,
                              void* d_out, int out_size, void* d_ws, size_t ws_size,
                              hipStream_t stream)
{
    const float* x    = (const float*)d_in[0];
    const int*   mask = (const int*)  d_in[1];
    const float* WQ_w = (const float*)d_in[2];
    const float* WQ_b = (const float*)d_in[3];
    const float* WK_w = (const float*)d_in[4];
    const float* WK_b = (const float*)d_in[5];
    const float* WV_w = (const float*)d_in[6];
    const float* WV_b = (const float*)d_in[7];
    const float* WO_w = (const float*)d_in[8];
    const float* WO_b = (const float*)d_in[9];
    const float* ln_g = (const float*)d_in[10];
    const float* ln_b = (const float*)d_in[11];
    const float* W1_w = (const float*)d_in[12];
    const float* W1_b = (const float*)d_in[13];
    const float* W2_w = (const float*)d_in[14];
    const float* W2_b = (const float*)d_in[15];
    float* out = (float*)d_out;

    char* w = (char*)d_ws;
    const size_t MB = 1024*1024;
    unsigned short* qkv  = (unsigned short*)(w + 0*MB);    // 48MB fused QKV
    unsigned short* Zb   = (unsigned short*)(w + 48*MB);   // 16MB
    unsigned short* xb   = (unsigned short*)(w + 64*MB);   // 16MB
    float*          rb   = (float*)         (w + 80*MB);   // 32MB
    unsigned short* wqkv = (unsigned short*)(w + 112*MB);  // 6MB fused weights
    unsigned short* wob  = (unsigned short*)(w + 118*MB);  // 2MB
    unsigned short* w1b  = (unsigned short*)(w + 120*MB);  // 8MB
    unsigned short* w2b  = (unsigned short*)(w + 128*MB);  // 8MB
    unsigned long long* mbits = (unsigned long long*)(w + 136*MB); // 2MB
    float* bqkv = (float*)(w + 48*MB);   // 12KB, dead before attn writes Zb here
    unsigned short* hln  = xb;                            // xb dead after QKV
    unsigned short* hmid = (unsigned short*)(w + 0*MB);   // qkv+Zb dead after WO

    // casts + bitmask + fused bias concat
    cast_bf16_k<<<2048, 256, 0, stream>>>(x,    xb,   (long)MROWS*DMODEL);
    cast_bf16_k<<<512,  256, 0, stream>>>(WQ_w, wqkv,               (long)DMODEL*DMODEL);
    cast_bf16_k<<<512,  256, 0, stream>>>(WK_w, wqkv + 1024*1024,   (long)DMODEL*DMODEL);
    cast_bf16_k<<<512,  256, 0, stream>>>(WV_w, wqkv + 2*1024*1024, (long)DMODEL*DMODEL);
    cast_bf16_k<<<512,  256, 0, stream>>>(WO_w, wob,  (long)DMODEL*DMODEL);
    cast_bf16_k<<<2048, 256, 0, stream>>>(W1_w, w1b,  (long)DFFN*DMODEL);
    cast_bf16_k<<<2048, 256, 0, stream>>>(W2_w, w2b,  (long)DMODEL*DFFN);
    maskbits_k<<<65536, 256, 0, stream>>>(mask, mbits);
    concat3_k<<<4, 256, 0, stream>>>(WQ_b, WK_b, WV_b, bqkv);

    // fused QKV projection (Q scaled by 1/8 * log2(e)); 768 blocks = 3 full rounds
    gemm8n<0, 16><<<dim3(768), dim3(512), 0, stream>>>(xb, wqkv, bqkv, nullptr, qkv,
                                                       MROWS, QKVS, DMODEL, 0.18033688f);
    // fused attention
    attn_k<<<dim3(1024), dim3(256), 0, stream>>>(qkv, mbits, Zb);
    // WO projection + residual 1 -> r (f32)
    gemm_nt<2><<<dim3(8, 64), dim3(256), 0, stream>>>(Zb, wob, WO_b, x, rb, MROWS, DMODEL, DMODEL, 1.0f);
    // pre-LN of FFN
    ln_k<<<MROWS, 256, 0, stream>>>(rb, ln_g, ln_b, hln);
    // FFN
    gemm8<1, 16><<<dim3(512), dim3(512), 0, stream>>>(hln, w1b, W1_b, hmid,
                                                      MROWS, DFFN, DMODEL, 1.0f);
    gemm8n<2, 64><<<dim3(256), dim3(512), 0, stream>>>(hmid, w2b, W2_b, rb, out,
                                                       MROWS, DMODEL, DFFN, 1.0f);
}

// Round 6
// 485.188 us; speedup vs baseline: 1.7148x; 1.0475x over previous
//
#include <hip/hip_runtime.h>

// Problem constants
#define BD      4
#define LSEQ    2048
#define DMODEL  1024
#define HHEADS  16
#define DKK     64
#define DFFN    4096
#define MROWS   (BD*LSEQ)   // 8192
#define QKS     2048        // Q|K fused row stride

typedef float  f32x4  __attribute__((ext_vector_type(4)));
typedef float  f32x16 __attribute__((ext_vector_type(16)));
typedef __bf16 bf16x8 __attribute__((ext_vector_type(8)));
typedef unsigned short u16x8 __attribute__((ext_vector_type(8)));
typedef unsigned int   u32x4 __attribute__((ext_vector_type(4)));

__device__ inline unsigned short f2bf(float x) {
    union { float f; unsigned u; } c; c.f = x;
    unsigned r = c.u + 0x7FFFu + ((c.u >> 16) & 1u);
    return (unsigned short)(r >> 16);
}

// ---------------- f32 -> bf16 cast ----------------
__global__ void cast_bf16_k(const float* __restrict__ in,
                            unsigned short* __restrict__ out, long n) {
    long i = ((long)blockIdx.x * blockDim.x + threadIdx.x) * 4;
    long stride = (long)gridDim.x * blockDim.x * 4;
    for (; i < n; i += stride) {
        float4 v = *(const float4*)(in + i);
        ushort4 o;
        o.x = f2bf(v.x); o.y = f2bf(v.y); o.z = f2bf(v.z); o.w = f2bf(v.w);
        *(ushort4*)(out + i) = o;
    }
}

// ---------------- bias concat (Q|K|V) ----------------
__global__ void concat3_k(const float* __restrict__ a, const float* __restrict__ b,
                          const float* __restrict__ c, float* __restrict__ o) {
    int i = blockIdx.x * 256 + threadIdx.x;
    if (i < 1024) { o[i] = a[i]; o[1024 + i] = b[i]; o[2048 + i] = c[i]; }
}

// ---------------- mask -> bitmask ----------------
__global__ __launch_bounds__(256) void maskbits_k(const int* __restrict__ m,
                                                  unsigned long long* __restrict__ bits) {
    const long gw = ((long)blockIdx.x * blockDim.x + threadIdx.x) >> 6;
    const int lane = threadIdx.x & 63;
    const int b   = (int)(gw >> 16);
    const int rem = (int)gw & 65535;
    const int q = rem >> 5, kt = rem & 31;
    const int v = m[((size_t)(b*LSEQ + q))*LSEQ + kt*64 + lane];
    const unsigned long long bal = __ballot(v != 0);
    if (lane == 0) bits[((size_t)(b*32 + kt))*LSEQ + q] = bal;
}

// ---------------- async global->LDS 16B ----------------
__device__ inline void gload16(const void* g, void* l) {
    __builtin_amdgcn_global_load_lds(
        (const __attribute__((address_space(1))) void*)g,
        (__attribute__((address_space(3))) void*)l, 16, 0, 0);
}

#define BAR() { __builtin_amdgcn_sched_barrier(0); __builtin_amdgcn_s_barrier(); __builtin_amdgcn_sched_barrier(0); }

// =================== 8-phase 256x256 NT GEMM (bf16) ===================
#define STAGE(XSEL, XPTR, h, tau, s)                                              \
  { const unsigned short* gs0 = (XPTR) + (size_t)((h)*128 + wid*8 + srow) * K + (tau)*64 + schk*8; \
    gload16(gs0, (void*)&sm[(s)][(XSEL)][(((h)*128 + wid*8)*64)]);                 \
    gload16(gs0 + (size_t)64*K, (void*)&sm[(s)][(XSEL)][(((h)*128 + 64 + wid*8)*64)]); }

#define LDA(dst, s, mi, kk) dst = *(const bf16x8*)(&sm[(s)][0][(wr*128 + (mi)*16 + r0)*64 + ((((kk)*4 + g) ^ (r0 & 7)) << 3)]);
#define LDB(dst, s, nj, kk) dst = *(const bf16x8*)(&sm[(s)][1][(wc*64  + (nj)*16 + r0)*64 + ((((kk)*4 + g) ^ (r0 & 7)) << 3)]);

#define PHASE_MFMA(q)                                                                                   \
    __builtin_amdgcn_s_setprio(1);                                                                      \
    _Pragma("unroll")                                                                                   \
    for (int nj = 0; nj < 4; ++nj) {                                                                    \
        acc[2*(q)][nj]   = __builtin_amdgcn_mfma_f32_16x16x32_bf16(af00, bq[nj][0], acc[2*(q)][nj],   0,0,0); \
        acc[2*(q)][nj]   = __builtin_amdgcn_mfma_f32_16x16x32_bf16(af01, bq[nj][1], acc[2*(q)][nj],   0,0,0); \
        acc[2*(q)+1][nj] = __builtin_amdgcn_mfma_f32_16x16x32_bf16(af10, bq[nj][0], acc[2*(q)+1][nj], 0,0,0); \
        acc[2*(q)+1][nj] = __builtin_amdgcn_mfma_f32_16x16x32_bf16(af11, bq[nj][1], acc[2*(q)+1][nj], 0,0,0); \
    }                                                                                                   \
    __builtin_amdgcn_s_setprio(0);

#define KTILE(s, tau)                                                        \
  {                                                                          \
    const int tp1 = (tau) + 1, tp2 = (tau) + 2;                              \
    bf16x8 bq[4][2];                                                         \
    bf16x8 af00, af01, af10, af11;                                           \
    _Pragma("unroll") for (int nj = 0; nj < 4; ++nj) {                       \
        LDB(bq[nj][0], s, nj, 0); LDB(bq[nj][1], s, nj, 1); }                \
    LDA(af00, s, 0, 0); LDA(af01, s, 0, 1);                                  \
    LDA(af10, s, 1, 0); LDA(af11, s, 1, 1);                                  \
    if (tp1 < NTT) { STAGE(0, Ab, 0, tp1, (s)^1); }                          \
    BAR(); PHASE_MFMA(0); BAR();                                             \
    LDA(af00, s, 2, 0); LDA(af01, s, 2, 1);                                  \
    LDA(af10, s, 3, 0); LDA(af11, s, 3, 1);                                  \
    if (tp1 < NTT) { STAGE(0, Ab, 1, tp1, (s)^1); }                          \
    if (tp2 < NTT) { STAGE(1, Bb, 0, tp2, (s)); }                            \
    BAR(); PHASE_MFMA(1); BAR();                                             \
    LDA(af00, s, 4, 0); LDA(af01, s, 4, 1);                                  \
    LDA(af10, s, 5, 0); LDA(af11, s, 5, 1);                                  \
    if (tp2 < NTT) { STAGE(1, Bb, 1, tp2, (s)); }                            \
    BAR(); PHASE_MFMA(2); BAR();                                             \
    LDA(af00, s, 6, 0); LDA(af01, s, 6, 1);                                  \
    LDA(af10, s, 7, 0); LDA(af11, s, 7, 1);                                  \
    if (tp2 < NTT)      { asm volatile("s_waitcnt vmcnt(4)" ::: "memory"); } \
    else if (tp1 < NTT) { asm volatile("s_waitcnt vmcnt(0)" ::: "memory"); } \
    BAR(); PHASE_MFMA(3); BAR();                                             \
  }

template<int MODE, int NTT>
__global__ __launch_bounds__(512, 1) void gemm8(const unsigned short* __restrict__ A,
                                                const unsigned short* __restrict__ B,
                                                const float* __restrict__ bias,
                                                unsigned short* __restrict__ Cout,
                                                int M, int N, int K, float scaleQ)
{
    __shared__ unsigned short sm[2][2][256*64];
    const int t   = threadIdx.x;
    const int wid = t >> 6, lane = t & 63;
    const int wr  = wid >> 2, wc = wid & 3;
    const int r0  = lane & 15, g = lane >> 4;

    const int nwg = gridDim.x;
    const int bid = (blockIdx.x & 7) * (nwg >> 3) + (blockIdx.x >> 3);
    const int ntn = N >> 8;
    const int bm  = (bid / ntn) << 8, bn = (bid % ntn) << 8;

    const int srow = lane >> 3;
    const int schk = (lane & 7) ^ srow;
    const unsigned short* Ab = A + (size_t)bm * K;
    const unsigned short* Bb = B + (size_t)bn * K;

    f32x4 acc[8][4] = {};

    STAGE(1, Bb, 0, 0, 0); STAGE(1, Bb, 1, 0, 0);
    STAGE(0, Ab, 0, 0, 0); STAGE(0, Ab, 1, 0, 0);
    STAGE(1, Bb, 0, 1, 1); STAGE(1, Bb, 1, 1, 1);
    asm volatile("s_waitcnt vmcnt(4)" ::: "memory");
    BAR();

#pragma unroll 1
    for (int i2 = 0; i2 < NTT/2; ++i2) {
        const int tau = 2*i2;
        KTILE(0, tau);
        KTILE(1, tau+1);
    }

#pragma unroll
    for (int mi = 0; mi < 8; ++mi) {
        const int row0 = bm + wr*128 + mi*16 + g*4;
#pragma unroll
        for (int nj = 0; nj < 4; ++nj) {
            const int col = bn + wc*64 + nj*16 + r0;
            const float bcol = bias[col];
#pragma unroll
            for (int rr = 0; rr < 4; ++rr) {
                float c = acc[mi][nj][rr] + bcol;
                if (MODE == 1) c = fmaxf(c, 0.f);
                Cout[(size_t)(row0 + rr) * N + col] = f2bf(c);
            }
        }
    }
}

// =================== 8-phase 256x128 NT GEMM variant ===================
// MODE 2: f32 out + residual. MODE 3: fused QKV epilogue -> qk rowmajor
// (Q scaled) + V transposed to vt[b*1024 + vcol][token].
#define STAGEA2(h, tau, s)                                                        \
  { const unsigned short* gs0 = Ab + (size_t)((h)*128 + wid*8 + srow) * K + (tau)*64 + schk*8; \
    gload16(gs0, (void*)&smA[(s)][(((h)*128 + wid*8)*64)]);                        \
    gload16(gs0 + (size_t)64*K, (void*)&smA[(s)][(((h)*128 + 64 + wid*8)*64)]); }

#define STAGEB2(tau, s)                                                           \
  { const unsigned short* gs0 = Bb + (size_t)(wid*8 + srow) * K + (tau)*64 + schk*8; \
    gload16(gs0, (void*)&smB[(s)][((wid*8)*64)]);                                  \
    gload16(gs0 + (size_t)64*K, (void*)&smB[(s)][((64 + wid*8)*64)]); }

#define LDA2(dst, s, mi, kk) dst = *(const bf16x8*)(&smA[(s)][(wr*128 + (mi)*16 + r0)*64 + ((((kk)*4 + g) ^ (r0 & 7)) << 3)]);
#define LDB2(dst, s, nj, kk) dst = *(const bf16x8*)(&smB[(s)][(wc*32  + (nj)*16 + r0)*64 + ((((kk)*4 + g) ^ (r0 & 7)) << 3)]);

#define PHASE_MFMA2(q)                                                                                  \
    __builtin_amdgcn_s_setprio(1);                                                                      \
    _Pragma("unroll")                                                                                   \
    for (int nj = 0; nj < 2; ++nj) {                                                                    \
        acc[2*(q)][nj]   = __builtin_amdgcn_mfma_f32_16x16x32_bf16(af00, bq[nj][0], acc[2*(q)][nj],   0,0,0); \
        acc[2*(q)][nj]   = __builtin_amdgcn_mfma_f32_16x16x32_bf16(af01, bq[nj][1], acc[2*(q)][nj],   0,0,0); \
        acc[2*(q)+1][nj] = __builtin_amdgcn_mfma_f32_16x16x32_bf16(af10, bq[nj][0], acc[2*(q)+1][nj], 0,0,0); \
        acc[2*(q)+1][nj] = __builtin_amdgcn_mfma_f32_16x16x32_bf16(af11, bq[nj][1], acc[2*(q)+1][nj], 0,0,0); \
    }                                                                                                   \
    __builtin_amdgcn_s_setprio(0);

#define KTILE2(s, tau)                                                       \
  {                                                                          \
    const int tp1 = (tau) + 1, tp2 = (tau) + 2;                              \
    bf16x8 bq[2][2];                                                         \
    bf16x8 af00, af01, af10, af11;                                           \
    _Pragma("unroll") for (int nj = 0; nj < 2; ++nj) {                       \
        LDB2(bq[nj][0], s, nj, 0); LDB2(bq[nj][1], s, nj, 1); }              \
    LDA2(af00, s, 0, 0); LDA2(af01, s, 0, 1);                                \
    LDA2(af10, s, 1, 0); LDA2(af11, s, 1, 1);                                \
    if (tp1 < NTT) { STAGEA2(0, tp1, (s)^1); }                               \
    BAR(); PHASE_MFMA2(0); BAR();                                            \
    LDA2(af00, s, 2, 0); LDA2(af01, s, 2, 1);                                \
    LDA2(af10, s, 3, 0); LDA2(af11, s, 3, 1);                                \
    if (tp1 < NTT) { STAGEA2(1, tp1, (s)^1); }                               \
    BAR(); PHASE_MFMA2(1); BAR();                                            \
    LDA2(af00, s, 4, 0); LDA2(af01, s, 4, 1);                                \
    LDA2(af10, s, 5, 0); LDA2(af11, s, 5, 1);                                \
    if (tp2 < NTT) { STAGEB2(tp2, (s)); }                                    \
    BAR(); PHASE_MFMA2(2); BAR();                                            \
    LDA2(af00, s, 6, 0); LDA2(af01, s, 6, 1);                                \
    LDA2(af10, s, 7, 0); LDA2(af11, s, 7, 1);                                \
    if (tp2 < NTT)      { asm volatile("s_waitcnt vmcnt(2)" ::: "memory"); } \
    else if (tp1 < NTT) { asm volatile("s_waitcnt vmcnt(0)" ::: "memory"); } \
    BAR(); PHASE_MFMA2(3); BAR();                                            \
  }

template<int MODE, int NTT>
__global__ __launch_bounds__(512, 1) void gemm8n(const unsigned short* __restrict__ A,
                                                 const unsigned short* __restrict__ B,
                                                 const float* __restrict__ bias,
                                                 const float* __restrict__ resid,
                                                 void* __restrict__ Cout,
                                                 unsigned short* __restrict__ vt,
                                                 int M, int N, int K, float scaleQ)
{
    __shared__ unsigned short smA[2][256*64];   // 64 KiB
    __shared__ unsigned short smB[2][128*64];   // 32 KiB
    const int t   = threadIdx.x;
    const int wid = t >> 6, lane = t & 63;
    const int wr  = wid >> 2, wc = wid & 3;
    const int r0  = lane & 15, g = lane >> 4;

    const int nwg = gridDim.x;
    const int bid = (blockIdx.x & 7) * (nwg >> 3) + (blockIdx.x >> 3);
    const int ntn = N >> 7;
    const int bm  = (bid / ntn) << 8, bn = (bid % ntn) << 7;

    const int srow = lane >> 3;
    const int schk = (lane & 7) ^ srow;
    const unsigned short* Ab = A + (size_t)bm * K;
    const unsigned short* Bb = B + (size_t)bn * K;

    f32x4 acc[8][2] = {};

    STAGEB2(0, 0);
    STAGEA2(0, 0, 0); STAGEA2(1, 0, 0);
    STAGEB2(1, 1);
    asm volatile("s_waitcnt vmcnt(2)" ::: "memory");
    BAR();

#pragma unroll 1
    for (int i2 = 0; i2 < NTT/2; ++i2) {
        const int tau = 2*i2;
        KTILE2(0, tau);
        KTILE2(1, tau+1);
    }

#pragma unroll
    for (int mi = 0; mi < 8; ++mi) {
        const int row0 = bm + wr*128 + mi*16 + g*4;
#pragma unroll
        for (int nj = 0; nj < 2; ++nj) {
            const int col = bn + wc*32 + nj*16 + r0;
            const float bcol = bias[col];
#pragma unroll
            for (int rr = 0; rr < 4; ++rr) {
                const int row = row0 + rr;
                if (MODE == 2) {
                    float c = acc[mi][nj][rr] + bcol;
                    ((float*)Cout)[(size_t)row * N + col] = c + resid[(size_t)row * N + col];
                }
            }
            if (MODE == 3) {
                if (col < 2048) {
                    const float sc = (col < 1024) ? scaleQ : 1.0f;
#pragma unroll
                    for (int rr = 0; rr < 4; ++rr)
                        ((unsigned short*)Cout)[(size_t)(row0 + rr) * QKS + col] =
                            f2bf((acc[mi][nj][rr] + bcol) * sc);
                } else {
                    const int vcol = col - 2048;
                    const int b = row0 >> 11, tok = row0 & 2047;
                    ushort4 h4;
                    h4.x = f2bf(acc[mi][nj][0] + bcol);
                    h4.y = f2bf(acc[mi][nj][1] + bcol);
                    h4.z = f2bf(acc[mi][nj][2] + bcol);
                    h4.w = f2bf(acc[mi][nj][3] + bcol);
                    *(ushort4*)&vt[((size_t)(b*1024 + vcol))*LSEQ + tok] = h4;
                }
            }
        }
    }
}

// ---------------- 128x128 NT GEMM (m97-structure) for WO ----------------
template<int MODE>
__global__ __launch_bounds__(256) void gemm_nt(const unsigned short* __restrict__ A,
                                               const unsigned short* __restrict__ B,
                                               const float* __restrict__ bias,
                                               const float* __restrict__ resid,
                                               void* __restrict__ Cout,
                                               int M, int N, int K, float scale)
{
    __shared__ unsigned short As[128*32];
    __shared__ unsigned short Bs[128*32];
    const int t    = threadIdx.x;
    const int w    = t >> 6, lane = t & 63;
    const int r0   = lane & 15, g = lane >> 4;
    const int wm   = (w >> 1) * 64, wn = (w & 1) * 64;
    const int bm   = blockIdx.y * 128, bn = blockIdx.x * 128;
    const int srow = t >> 2, scol = (t & 3) * 8;

    const unsigned short* Ag = A + (size_t)(bm + srow) * K + scol;
    const unsigned short* Bg = B + (size_t)(bn + srow) * K + scol;
    unsigned short* AsW = As + w * 512;
    unsigned short* BsW = Bs + w * 512;

    f32x4 acc[4][4] = {};

    for (int kt = 0; kt < K; kt += 32) {
        gload16(Ag + kt,                AsW);
        gload16(Ag + (size_t)64*K + kt, AsW + 2048);
        gload16(Bg + kt,                BsW);
        gload16(Bg + (size_t)64*K + kt, BsW + 2048);
        __syncthreads();
        bf16x8 af[4], bfr[4];
#pragma unroll
        for (int i = 0; i < 4; ++i)
            af[i] = *(const bf16x8*)(As + (wm + i*16 + r0)*32 + g*8);
#pragma unroll
        for (int j = 0; j < 4; ++j)
            bfr[j] = *(const bf16x8*)(Bs + (wn + j*16 + r0)*32 + g*8);
#pragma unroll
        for (int i = 0; i < 4; ++i)
#pragma unroll
            for (int j = 0; j < 4; ++j)
                acc[i][j] = __builtin_amdgcn_mfma_f32_16x16x32_bf16(af[i], bfr[j], acc[i][j], 0, 0, 0);
        __syncthreads();
    }

#pragma unroll
    for (int i = 0; i < 4; ++i) {
        const int row0 = bm + wm + i*16 + g*4;
#pragma unroll
        for (int j = 0; j < 4; ++j) {
            const int col = bn + wn + j*16 + r0;
            const float bcol = bias[col];
#pragma unroll
            for (int rr = 0; rr < 4; ++rr) {
                const int row = row0 + rr;
                float c = (acc[i][j][rr] + bcol) * scale;
                if (MODE == 2) {
                    ((float*)Cout)[(size_t)row * N + col] = c + resid[(size_t)row * N + col];
                } else {
                    if (MODE == 1) c = fmaxf(c, 0.f);
                    ((unsigned short*)Cout)[(size_t)row * N + col] = f2bf(c);
                }
            }
        }
    }
}

// ---------------- fused flash attention ----------------
// log2-domain softmax; Q in regs; K AND V^T staged via source-swizzled
// global_load_lds, both double-buffered; one barrier per tile.
#define MFILL   (-47272.79f)    /* -32767 * log2(e) */
#define DEFTHR  (11.5415603f)   /* 8 * log2(e) */
__global__ __launch_bounds__(256) void attn_k(
    const unsigned short* __restrict__ QK,
    const unsigned short* __restrict__ VT,
    const unsigned long long* __restrict__ MBits,
    unsigned short* __restrict__ Z)
{
    __shared__ unsigned short Ks[2][64*64];   // 16 KB
    __shared__ unsigned short Vs[2][64*64];   // 16 KB
    __shared__ float Sc[4*32];

    const int t    = threadIdx.x;
    const int w    = t >> 6, lane = t & 63;
    const int q31  = lane & 31, hi = lane >> 5;

    const int bid = blockIdx.x;
    const int sw  = (bid & 7) * 128 + (bid >> 3);
    const int qt  = sw & 15, h = (sw >> 4) & 15, b = sw >> 8;
    const int qw  = qt * 128 + w * 32;

    // ---- Q fragments in registers (pre-scaled by 1/8*log2e) ----
    const unsigned short* Qg = QK + ((size_t)(b*LSEQ + qw + q31))*QKS + h*DKK + hi*8;
    bf16x8 qf[4];
#pragma unroll
    for (int ds = 0; ds < 4; ++ds)
        qf[ds] = *(const bf16x8*)(Qg + ds*16);

    // staging mappings (wave w covers rows w*8..w*8+7 and +32)
    const int srow = w*8 + (lane>>3);
    const int schk = (lane & 7) ^ (srow & 7);
    const unsigned short* Kg = QK + ((size_t)(b*LSEQ))*QKS + 1024 + h*DKK;
    const unsigned short* Vg = VT + ((size_t)(b*1024 + h*DKK))*LSEQ;

    float m_r = MFILL, l_r = 0.f;
    f32x16 z0, z1;
#pragma unroll
    for (int r = 0; r < 16; ++r) { z0[r] = 0.f; z1[r] = 0.f; }

    // ---- prologue: stage tile 0 + mask word ----
    gload16(Kg + (size_t)srow*QKS      + schk*8, &Ks[0][w*512]);
    gload16(Kg + (size_t)(32+srow)*QKS + schk*8, &Ks[0][w*512] + 2048);
    gload16(Vg + (size_t)srow*LSEQ      + schk*8, &Vs[0][w*512]);
    gload16(Vg + (size_t)(32+srow)*LSEQ + schk*8, &Vs[0][w*512] + 2048);
    unsigned long long mw = MBits[((size_t)(b*32 + 0))*LSEQ + (qw + q31)];

    for (int kt = 0; kt < LSEQ/64; ++kt) {
        const int cur = kt & 1;
        __syncthreads();   // drains vmcnt: buf[cur] ready; buf[cur^1] free

        // early-issue next tile's loads + mask word
        const int ktn = (kt < LSEQ/64 - 1) ? kt + 1 : kt;
        const int k0n = ktn * 64;
        gload16(Kg + (size_t)(k0n + srow)*QKS      + schk*8, &Ks[cur^1][w*512]);
        gload16(Kg + (size_t)(k0n + 32 + srow)*QKS + schk*8, &Ks[cur^1][w*512] + 2048);
        gload16(Vg + (size_t)srow*LSEQ      + k0n + schk*8, &Vs[cur^1][w*512]);
        gload16(Vg + (size_t)(32+srow)*LSEQ + k0n + schk*8, &Vs[cur^1][w*512] + 2048);
        const unsigned long long mwn = MBits[((size_t)(b*32 + ktn))*LSEQ + (qw + q31)];

        const unsigned long long sh = mw >> (hi*4);
        const unsigned md0 = (unsigned)sh, md1 = (unsigned)(sh >> 32);

        // ---- QK^T (swapped): s = K_tile * Q^T ----
        f32x16 s0, s1;
#pragma unroll
        for (int r = 0; r < 16; ++r) { s0[r] = 0.f; s1[r] = 0.f; }
        __builtin_amdgcn_s_setprio(1);
#pragma unroll
        for (int ds = 0; ds < 4; ++ds) {
            const int slot = ((ds*2 + hi) ^ (q31 & 7)) << 3;
            bf16x8 kf0 = *(const bf16x8*)(&Ks[cur][ q31     *64 + slot]);
            bf16x8 kf1 = *(const bf16x8*)(&Ks[cur][(32+q31)*64 + slot]);
            s0 = __builtin_amdgcn_mfma_f32_32x32x16_bf16(kf0, qf[ds], s0, 0, 0, 0);
            s1 = __builtin_amdgcn_mfma_f32_32x32x16_bf16(kf1, qf[ds], s1, 0, 0, 0);
        }
        __builtin_amdgcn_s_setprio(0);

        // ---- mask fill ----
#pragma unroll
        for (int r = 0; r < 16; ++r) {
            const int kb = (r & 3) + 8*(r >> 2);
            if (!((md0 >> kb) & 1)) s0[r] = MFILL;
            if (!((md1 >> kb) & 1)) s1[r] = MFILL;
        }

        // ---- row max ----
        float tm = fmaxf(s0[0], s1[0]);
#pragma unroll
        for (int r = 1; r < 16; ++r) tm = fmaxf(tm, fmaxf(s0[r], s1[r]));
        {
            float ta = tm, tb = tm;
            asm volatile("v_permlane32_swap_b32 %0, %1" : "+v"(ta), "+v"(tb));
            tm = fmaxf(tm, hi ? ta : tb);
        }

        // ---- defer-max rescale (rare) ----
        if (__any(tm > m_r + DEFTHR)) {
            const float nm   = fmaxf(m_r, tm);
            const float corr = exp2f(m_r - nm);
            Sc[w*32 + q31] = corr;
            l_r *= corr;
            m_r  = nm;
#pragma unroll
            for (int r = 0; r < 16; ++r) {
                const int row = (r & 3) + 8*(r >> 2) + 4*hi;
                const float cr = Sc[w*32 + row];
                z0[r] *= cr; z1[r] *= cr;
            }
        }

        // ---- exp (log2 domain) ----
#pragma unroll
        for (int r = 0; r < 16; ++r) {
            s0[r] = exp2f(s0[r] - m_r);
            s1[r] = exp2f(s1[r] - m_r);
        }
        // ---- row sum ----
        float r4[8];
#pragma unroll
        for (int r = 0; r < 8; ++r)
            r4[r] = (s0[2*r] + s0[2*r+1]) + (s1[2*r] + s1[2*r+1]);
        float rs = ((r4[0]+r4[1]) + (r4[2]+r4[3])) + ((r4[4]+r4[5]) + (r4[6]+r4[7]));
        {
            float ra = rs, rb = rs;
            asm volatile("v_permlane32_swap_b32 %0, %1" : "+v"(ra), "+v"(rb));
            rs += hi ? ra : rb;
        }
        l_r += rs;

        // ---- P->bf16 A-frag per ks + PV MFMA (B-frag from Vs rows d) ----
        __builtin_amdgcn_s_setprio(1);
#pragma unroll
        for (int half = 0; half < 2; ++half) {
#pragma unroll
            for (int sub = 0; sub < 2; ++sub) {
                const int base = sub*8;
                unsigned wa, wb, wc2, wd;
                float p0 = half ? s1[base+0] : s0[base+0];
                float p1 = half ? s1[base+1] : s0[base+1];
                float p2 = half ? s1[base+2] : s0[base+2];
                float p3 = half ? s1[base+3] : s0[base+3];
                float p4 = half ? s1[base+4] : s0[base+4];
                float p5 = half ? s1[base+5] : s0[base+5];
                float p6 = half ? s1[base+6] : s0[base+6];
                float p7 = half ? s1[base+7] : s0[base+7];
                asm("v_cvt_pk_bf16_f32 %0, %1, %2" : "=v"(wa) : "v"(p0), "v"(p1));
                asm("v_cvt_pk_bf16_f32 %0, %1, %2" : "=v"(wb) : "v"(p4), "v"(p5));
                asm("v_cvt_pk_bf16_f32 %0, %1, %2" : "=v"(wc2) : "v"(p2), "v"(p3));
                asm("v_cvt_pk_bf16_f32 %0, %1, %2" : "=v"(wd) : "v"(p6), "v"(p7));
                asm volatile("v_permlane32_swap_b32 %0, %1" : "+v"(wa), "+v"(wb));
                asm volatile("v_permlane32_swap_b32 %0, %1" : "+v"(wc2), "+v"(wd));
                u32x4 pu; pu[0] = wa; pu[1] = wc2; pu[2] = wb; pu[3] = wd;
                bf16x8 pa = __builtin_bit_cast(bf16x8, pu);
                const int ks = half*2 + sub;
                const int slot = ((ks*2 + hi) ^ (q31 & 7)) << 3;
                bf16x8 vf0 = *(const bf16x8*)(&Vs[cur][ q31     *64 + slot]);
                bf16x8 vf1 = *(const bf16x8*)(&Vs[cur][(32+q31)*64 + slot]);
                z0 = __builtin_amdgcn_mfma_f32_32x32x16_bf16(pa, vf0, z0, 0, 0, 0);
                z1 = __builtin_amdgcn_mfma_f32_32x32x16_bf16(pa, vf1, z1, 0, 0, 0);
            }
        }
        __builtin_amdgcn_s_setprio(0);

        mw = mwn;
    }

    // ---- epilogue ----
    Sc[w*32 + q31] = l_r;
    unsigned short* Zb = Z + ((size_t)(b*LSEQ + qw))*DMODEL + h*DKK + q31;
#pragma unroll
    for (int r = 0; r < 16; ++r) {
        const int row = (r & 3) + 8*(r >> 2) + 4*hi;
        const float rl = 1.0f / Sc[w*32 + row];
        Zb[(size_t)row*DMODEL]      = f2bf(z0[r] * rl);
        Zb[(size_t)row*DMODEL + 32] = f2bf(z1[r] * rl);
    }
}

// ---------------- LayerNorm (f32 in -> bf16 out) ----------------
__global__ __launch_bounds__(256) void ln_k(const float* __restrict__ r,
                                            const float* __restrict__ gam,
                                            const float* __restrict__ bet,
                                            unsigned short* __restrict__ out)
{
    const int row = blockIdx.x;
    const int t = threadIdx.x;
    const float* rp = r + (size_t)row * DMODEL;
    float4 v = *(const float4*)(rp + t*4);
    float s  = v.x + v.y + v.z + v.w;
    float s2 = v.x*v.x + v.y*v.y + v.z*v.z + v.w*v.w;
#pragma unroll
    for (int off = 32; off >= 1; off >>= 1) {
        s  += __shfl_xor(s,  off);
        s2 += __shfl_xor(s2, off);
    }
    __shared__ float red[8];
    const int wv = t >> 6;
    if ((t & 63) == 0) { red[wv] = s; red[4 + wv] = s2; }
    __syncthreads();
    s  = red[0] + red[1] + red[2] + red[3];
    s2 = red[4] + red[5] + red[6] + red[7];
    const float mu   = s  * (1.f/DMODEL);
    const float var  = s2 * (1.f/DMODEL) - mu*mu;
    const float rstd = rsqrtf(var + 1e-5f);
    float4 gv = *(const float4*)(gam + t*4);
    float4 bv = *(const float4*)(bet + t*4);
    ushort4 o;
    o.x = f2bf((v.x - mu)*rstd*gv.x + bv.x);
    o.y = f2bf((v.y - mu)*rstd*gv.y + bv.y);
    o.z = f2bf((v.z - mu)*rstd*gv.z + bv.z);
    o.w = f2bf((v.w - mu)*rstd*gv.w + bv.w);
    *(ushort4*)(out + (size_t)row * DMODEL + t*4) = o;
}

extern "C" void kernel_launch(void* const* d_in, const int* in_sizes, int n_in,
                              void* d_out, int out_size, void* d_ws, size_t ws_size,
                              hipStream_t stream)
{
    const float* x    = (const float*)d_in[0];
    const int*   mask = (const int*)  d_in[1];
    const float* WQ_w = (const float*)d_in[2];
    const float* WQ_b = (const float*)d_in[3];
    const float* WK_w = (const float*)d_in[4];
    const float* WK_b = (const float*)d_in[5];
    const float* WV_w = (const float*)d_in[6];
    const float* WV_b = (const float*)d_in[7];
    const float* WO_w = (const float*)d_in[8];
    const float* WO_b = (const float*)d_in[9];
    const float* ln_g = (const float*)d_in[10];
    const float* ln_b = (const float*)d_in[11];
    const float* W1_w = (const float*)d_in[12];
    const float* W1_b = (const float*)d_in[13];
    const float* W2_w = (const float*)d_in[14];
    const float* W2_b = (const float*)d_in[15];
    float* out = (float*)d_out;

    char* w = (char*)d_ws;
    const size_t MB = 1024*1024;
    unsigned short* qk   = (unsigned short*)(w + 0*MB);    // 32MB  Q|K rowmajor
    unsigned short* vtb  = (unsigned short*)(w + 32*MB);   // 32MB  V^T
    unsigned short* shr  = (unsigned short*)(w + 64*MB);   // 16MB  xb / Zb / hln
    float*          rb   = (float*)         (w + 80*MB);   // 32MB  (bqkv early)
    unsigned short* wqkv = (unsigned short*)(w + 112*MB);  // 6MB
    unsigned short* wob  = (unsigned short*)(w + 118*MB);  // 2MB
    unsigned short* w1b  = (unsigned short*)(w + 120*MB);  // 8MB
    unsigned short* w2b  = (unsigned short*)(w + 128*MB);  // 8MB
    unsigned long long* mbits = (unsigned long long*)(w + 136*MB); // 2MB -> 138MB
    float* bqkv = (float*)rb;                              // dead before WO writes rb
    unsigned short* xb   = shr;
    unsigned short* Zb   = shr;
    unsigned short* hln  = shr;
    unsigned short* hmid = (unsigned short*)(w + 0*MB);    // qk+vtb dead after attn

    // casts + bitmask + fused bias concat
    cast_bf16_k<<<2048, 256, 0, stream>>>(x,    xb,   (long)MROWS*DMODEL);
    cast_bf16_k<<<512,  256, 0, stream>>>(WQ_w, wqkv,               (long)DMODEL*DMODEL);
    cast_bf16_k<<<512,  256, 0, stream>>>(WK_w, wqkv + 1024*1024,   (long)DMODEL*DMODEL);
    cast_bf16_k<<<512,  256, 0, stream>>>(WV_w, wqkv + 2*1024*1024, (long)DMODEL*DMODEL);
    cast_bf16_k<<<512,  256, 0, stream>>>(WO_w, wob,  (long)DMODEL*DMODEL);
    cast_bf16_k<<<2048, 256, 0, stream>>>(W1_w, w1b,  (long)DFFN*DMODEL);
    cast_bf16_k<<<2048, 256, 0, stream>>>(W2_w, w2b,  (long)DMODEL*DFFN);
    maskbits_k<<<65536, 256, 0, stream>>>(mask, mbits);
    concat3_k<<<4, 256, 0, stream>>>(WQ_b, WK_b, WV_b, bqkv);

    // fused QKV projection; V written transposed (MODE 3)
    gemm8n<3, 16><<<dim3(768), dim3(512), 0, stream>>>(xb, wqkv, bqkv, nullptr, qk, vtb,
                                                       MROWS, 3072, DMODEL, 0.18033688f);
    // fused attention
    attn_k<<<dim3(1024), dim3(256), 0, stream>>>(qk, vtb, mbits, Zb);
    // WO projection + residual 1 -> r (f32)
    gemm_nt<2><<<dim3(8, 64), dim3(256), 0, stream>>>(Zb, wob, WO_b, x, rb, MROWS, DMODEL, DMODEL, 1.0f);
    // pre-LN of FFN
    ln_k<<<MROWS, 256, 0, stream>>>(rb, ln_g, ln_b, hln);
    // FFN
    gemm8<1, 16><<<dim3(512), dim3(512), 0, stream>>>(hln, w1b, W1_b, hmid,
                                                      MROWS, DFFN, DMODEL, 1.0f);
    gemm8n<2, 64><<<dim3(256), dim3(512), 0, stream>>>(hmid, w2b, W2_b, rb, out, nullptr,
                                                       MROWS, DMODEL, DFFN, 1.0f);
}